// Round 3
// baseline (421.895 us; speedup 1.0000x reference)
//
#include <hip/hip_runtime.h>
#include <stdint.h>

// Problem constants (B,S,H)=(2,2048,2048), NH=16, NKV=2, HD=128, theta=1e6
#define Bsz  2
#define Ssz  2048
#define Hsz  2048
#define NHh  16
#define NKVh 2
#define HDd  128
#define NQKV 2560   // H + 2*KV = 2048 + 512

typedef __attribute__((ext_vector_type(8))) short bfrag;  // 8 x bf16 (4 VGPRs)
typedef __attribute__((ext_vector_type(4))) float facc;   // MFMA f32 accum

#define AS1 __attribute__((address_space(1)))
#define AS3 __attribute__((address_space(3)))

__device__ __forceinline__ ushort f2bf(float x){
  union { float f; uint32_t u; } v; v.f = x;
  return (ushort)((v.u + 0x7fffu + ((v.u >> 16) & 1u)) >> 16);
}
__device__ __forceinline__ float bf2f(ushort x){
  union { uint32_t u; float f; } v; v.u = ((uint32_t)x) << 16; return v.f;
}

// ---- fp32 -> bf16 bulk convert (X) ----
__global__ void k_convert(const float* __restrict__ in, ushort* __restrict__ out){
  const size_t i = ((size_t)blockIdx.x * 256 + threadIdx.x) * 4;
  const float4 v = *(const float4*)(in + i);
  ushort4 o;
  o.x = f2bf(v.x); o.y = f2bf(v.y); o.z = f2bf(v.z); o.w = f2bf(v.w);
  *(ushort4*)(out + i) = o;
}

// ---- transpose-convert: in (2048 x N) f32 row-major -> out bf16 rows (rowoff+n), ld 2048 ----
__global__ void k_transpose(const float* __restrict__ in, ushort* __restrict__ out,
                            int N, int rowoff){
  __shared__ float t[32][33];
  const int k0 = blockIdx.x * 32, n0 = blockIdx.y * 32;
  const int tx = threadIdx.x, ty = threadIdx.y; // 32 x 8
#pragma unroll
  for (int i = 0; i < 4; ++i)
    t[ty + i*8][tx] = in[(size_t)(k0 + ty + i*8) * N + n0 + tx];
  __syncthreads();
#pragma unroll
  for (int i = 0; i < 4; ++i)
    out[(size_t)(rowoff + n0 + ty + i*8) * 2048 + k0 + tx] = f2bf(t[tx][ty + i*8]);
}

// ---- concat biases (fp32) ----
__global__ void k_bias(const float* __restrict__ bq, const float* __restrict__ bk,
                       const float* __restrict__ bv, float* __restrict__ o){
  const int i = blockIdx.x * 256 + threadIdx.x;
  if (i < 2048)      o[i] = bq[i];
  else if (i < 2304) o[i] = bk[i - 2048];
  else if (i < 2560) o[i] = bv[i - 2304];
}

// ---- RoPE cos/sin table from position_ids ----
__global__ void k_ropetab(const int* __restrict__ pos, float* __restrict__ cosb,
                          float* __restrict__ sinb){
  const int s = blockIdx.x, j = threadIdx.x; // 64 threads
  const float p = (float)pos[s];
  const float fr = expf(-(float)j * (13.815510557964274f / 64.f)); // 1/theta^(j/64)
  const float t = p * fr;
  cosb[s*64 + j] = cosf(t);
  sinb[s*64 + j] = sinf(t);
}

// ---- m97-structure bf16 GEMM: C[M,N] = A[M,K] * Bt[N,K]^T (+bias) ----
template<bool HAS_BIAS, bool OUT_BF16>
__global__ __launch_bounds__(256) void k_gemm(const ushort* __restrict__ A,
                                              const ushort* __restrict__ Bt,
                                              const float* __restrict__ bias,
                                              void* __restrict__ Cout, int N, int K){
  __shared__ ushort As[128*64];
  __shared__ ushort Bs[128*64];
  const int m0 = blockIdx.x * 128;
  const int n0 = blockIdx.y * 128;
  const int tid = threadIdx.x;
  const int wave = tid >> 6, lane = tid & 63;
  const int wm = wave >> 1, wn = wave & 1;
  const int lrow = lane >> 4, lcol = lane & 15;
  const int srow = lane >> 3;          // 0..7 rows within a 1KB chunk
  const int scol = (lane & 7) * 8;     // element offset within 64-elem k-slice
  facc acc[4][4] = {};
  for (int k0 = 0; k0 < K; k0 += 64){
#pragma unroll
    for (int i = 0; i < 8; ++i){
      const int c = wave*8 + i;        // 0..31; <16 = A chunks, else B chunks
      if (c < 16){
        const ushort* g = A + (size_t)(m0 + c*8 + srow) * K + k0 + scol;
        __builtin_amdgcn_global_load_lds((const AS1 void*)g, (AS3 void*)(As + c*512), 16, 0, 0);
      } else {
        const ushort* g = Bt + (size_t)(n0 + (c-16)*8 + srow) * K + k0 + scol;
        __builtin_amdgcn_global_load_lds((const AS1 void*)g, (AS3 void*)(Bs + (c-16)*512), 16, 0, 0);
      }
    }
    __syncthreads();
#pragma unroll
    for (int kk = 0; kk < 2; ++kk){
      bfrag af[4], bf[4];
#pragma unroll
      for (int mi = 0; mi < 4; ++mi)
        af[mi] = *(const bfrag*)(As + (wm*64 + mi*16 + lcol)*64 + kk*32 + lrow*8);
#pragma unroll
      for (int ni = 0; ni < 4; ++ni)
        bf[ni] = *(const bfrag*)(Bs + (wn*64 + ni*16 + lcol)*64 + kk*32 + lrow*8);
#pragma unroll
      for (int mi = 0; mi < 4; ++mi)
#pragma unroll
        for (int ni = 0; ni < 4; ++ni)
          acc[mi][ni] = __builtin_amdgcn_mfma_f32_16x16x32_bf16(af[mi], bf[ni], acc[mi][ni], 0, 0, 0);
    }
    __syncthreads();
  }
#pragma unroll
  for (int mi = 0; mi < 4; ++mi){
#pragma unroll
    for (int ni = 0; ni < 4; ++ni){
      const int col = n0 + wn*64 + ni*16 + lcol;
      const float bsv = HAS_BIAS ? bias[col] : 0.f;
#pragma unroll
      for (int r = 0; r < 4; ++r){
        const size_t row = (size_t)m0 + wm*64 + mi*16 + lrow*4 + r;
        const float v = acc[mi][ni][r] + bsv;
        if (OUT_BF16) ((ushort*)Cout)[row * N + col] = f2bf(v);
        else          ((float*) Cout)[row * N + col] = v;
      }
    }
  }
}

// ---- in-place RoPE on q (cols 0..2047) and k (cols 2048..2303) of qkv ----
__global__ void k_rope(ushort* __restrict__ qkv, const float* __restrict__ cosb,
                       const float* __restrict__ sinb){
  const int s = blockIdx.x, b = blockIdx.y;
  ushort* rp = qkv + ((size_t)(b*Ssz + s)) * NQKV;
  const float* cb = cosb + s*64;
  const float* sb = sinb + s*64;
  for (int i = threadIdx.x; i < 18*64; i += 256){  // 16 q-heads + 2 kv-heads
    const int hh = i >> 6, d = i & 63;
    ushort* p = rp + hh*128 + d;
    const float x1 = bf2f(p[0]), x2 = bf2f(p[64]);
    const float c = cb[d], sn = sb[d];
    p[0]  = f2bf(x1*c  - x2*sn);
    p[64] = f2bf(x1*sn + x2*c);
  }
}

// ---- V relayout: qkv cols [2304,2560) (b,s,kv,d) -> vt (b,kv,d,s) ----
__global__ void k_vt(const ushort* __restrict__ qkv, ushort* __restrict__ vt){
  __shared__ ushort t[64][65];
  const int s0 = blockIdx.x * 64, d0 = blockIdx.y * 64;
  const int bkv = blockIdx.z, b = bkv >> 1, kv = bkv & 1;
  for (int i = threadIdx.x; i < 4096; i += 256){
    const int sl = i >> 6, dl = i & 63;
    t[sl][dl] = qkv[(size_t)(b*Ssz + s0 + sl)*NQKV + 2304 + kv*128 + d0 + dl];
  }
  __syncthreads();
  for (int i = threadIdx.x; i < 4096; i += 256){
    const int dl = i >> 6, sl = i & 63;
    vt[((size_t)(bkv*128 + d0 + dl))*Ssz + s0 + sl] = t[sl][dl];
  }
}

// ---- causal GQA flash attention: swapped QK^T (S^T via mfma(K,Q)) ----
// Lane owns q-row (lane&15): softmax max/sum = in-lane tree + 2 shfl_xor.
// Paired q-tiles A=p, B=31-p for balance; async reg-staged K/V (T14);
// defer-max rescale skip (T13, THR=8).
__global__ __launch_bounds__(256) void k_attn(const ushort* __restrict__ qkv,
                                              const ushort* __restrict__ vt,
                                              ushort* __restrict__ out){
  __shared__ __attribute__((aligned(16))) char klds[64*272];     // 64 x (128 bf16 + 16B pad)
  __shared__ __attribute__((aligned(16))) char vlds[128*144];    // 128 x (64 bf16 + 16B pad)
  __shared__ __attribute__((aligned(16))) char plds[4*2*2304];   // per-wave, A+B P buffers
  const int p = blockIdx.x, h = blockIdx.y, b = blockIdx.z;
  const int qtA = p, qtB = 31 - p;
  const int kvh = h >> 3;                 // rep = NH/NKV = 8
  const int tid = threadIdx.x, wave = tid >> 6, lane = tid & 63;
  const int lrow = lane >> 4, lcol = lane & 15;

  bfrag qfA[4], qfB[4];
  {
    const ushort* qa = qkv + ((size_t)b*Ssz + qtA*64 + wave*16 + lcol)*NQKV + h*HDd + lrow*8;
    const ushort* qb = qkv + ((size_t)b*Ssz + qtB*64 + wave*16 + lcol)*NQKV + h*HDd + lrow*8;
#pragma unroll
    for (int kk = 0; kk < 4; ++kk){
      qfA[kk] = *(const bfrag*)(qa + kk*32);
      qfB[kk] = *(const bfrag*)(qb + kk*32);
    }
  }
  facc accA[8] = {}, accB[8] = {};
  float mA = -1e30f, lA = 0.f, mB = -1e30f, lB = 0.f;  // per-lane scalars (q = lcol)

  const ushort* kb = qkv + (size_t)b*Ssz*NQKV + Hsz + kvh*HDd;
  const ushort* vb = vt + ((size_t)(b*NKVh + kvh))*HDd*Ssz;
  char* pwB = plds + wave*4608;
  char* pwA = pwB + 2304;
  const int qloc = wave*16 + lcol;        // q row within the 64-row q-tile

  int4 kreg[4], vreg[4];                  // async staging registers (T14)
  auto load_regs = [&](int t){
#pragma unroll
    for (int i = 0; i < 4; ++i){
      const int c = tid + 256*i;
      kreg[i] = *(const int4*)((const char*)(kb + (size_t)(t*64 + (c>>4))*NQKV) + (c&15)*16);
    }
#pragma unroll
    for (int i = 0; i < 4; ++i){
      const int c = tid + 256*i;
      vreg[i] = *(const int4*)((const char*)(vb + (size_t)(c>>3)*Ssz + t*64) + (c&7)*16);
    }
  };
  auto write_lds = [&](){
#pragma unroll
    for (int i = 0; i < 4; ++i){
      const int c = tid + 256*i;
      *(int4*)(klds + (c>>4)*272 + (c&15)*16) = kreg[i];
    }
#pragma unroll
    for (int i = 0; i < 4; ++i){
      const int c = tid + 256*i;
      *(int4*)(vlds + (c>>3)*144 + (c&7)*16) = vreg[i];
    }
  };

  // one tile-step: swapped QK^T -> in-lane softmax -> P pack -> PV
  auto step = [&](int t, int qx, bfrag* qf, facc* acc, float& m, float& l, char* pw){
    facc sc[4] = {};
#pragma unroll
    for (int kk = 0; kk < 4; ++kk){        // S^T = K * Q^T: 16 MFMA
#pragma unroll
      for (int nt = 0; nt < 4; ++nt){
        const bfrag kf = *(const bfrag*)(klds + (nt*16 + lcol)*272 + kk*64 + lrow*16);
        sc[nt] = __builtin_amdgcn_mfma_f32_16x16x32_bf16(kf, qf[kk], sc[nt], 0, 0, 0);
      }
    }
    const bool diag = (t == qx);
    float e[4][4];
    float tm = -1e30f;
#pragma unroll
    for (int nt = 0; nt < 4; ++nt){
#pragma unroll
      for (int r = 0; r < 4; ++r){
        float sv = sc[nt][r] * 0.088388347648318447f;   // 1/sqrt(128)
        if (diag && (nt*16 + lrow*4 + r) > qloc) sv = -1e30f;
        e[nt][r] = sv;
        tm = fmaxf(tm, sv);
      }
    }
    tm = fmaxf(tm, __shfl_xor(tm, 16));
    tm = fmaxf(tm, __shfl_xor(tm, 32));
    float mn = m, corr = 1.f;
    if (!__all(tm <= m + 8.f)){            // defer-max: skip rescale when bounded
      mn = fmaxf(m, tm);
      corr = __expf(m - mn);
#pragma unroll
      for (int r = 0; r < 4; ++r){
        const float ct = __shfl(corr, lrow*4 + r);
#pragma unroll
        for (int dt = 0; dt < 8; ++dt) acc[dt][r] *= ct;
      }
      m = mn;
    }
    float rs = 0.f;
#pragma unroll
    for (int nt = 0; nt < 4; ++nt)
#pragma unroll
      for (int r = 0; r < 4; ++r){
        const float ev = __expf(e[nt][r] - mn);
        e[nt][r] = ev; rs += ev;
      }
    rs += __shfl_xor(rs, 16);
    rs += __shfl_xor(rs, 32);
    l = l*corr + rs;
#pragma unroll
    for (int nt = 0; nt < 4; ++nt){        // P row-chunk -> LDS: 4 x ds_write_b64
      ushort4 w;
      w.x = f2bf(e[nt][0]); w.y = f2bf(e[nt][1]);
      w.z = f2bf(e[nt][2]); w.w = f2bf(e[nt][3]);
      *(ushort4*)(pw + lcol*144 + nt*32 + lrow*8) = w;
    }
    asm volatile("s_waitcnt lgkmcnt(0)" ::: "memory");
#pragma unroll
    for (int kk2 = 0; kk2 < 2; ++kk2){     // PV: 16 MFMA
      const bfrag pa = *(const bfrag*)(pw + lcol*144 + kk2*64 + lrow*16);
#pragma unroll
      for (int dt = 0; dt < 8; ++dt){
        const bfrag vf = *(const bfrag*)(vlds + (dt*16 + lcol)*144 + kk2*64 + lrow*16);
        acc[dt] = __builtin_amdgcn_mfma_f32_16x16x32_bf16(pa, vf, acc[dt], 0, 0, 0);
      }
    }
  };

  load_regs(0);
  write_lds();
  __syncthreads();
  for (int t = 0; t <= qtB; ++t){
    const bool more = (t < qtB);
    if (more) load_regs(t + 1);            // issue early; latency hides under compute
    step(t, qtB, qfB, accB, mB, lB, pwB);
    if (t <= qtA) step(t, qtA, qfA, accA, mA, lA, pwA);
    __syncthreads();                       // all waves done reading klds/vlds
    if (more) write_lds();                 // vmcnt drained here by compiler
    __syncthreads();
  }

  float lAt[4], lBt[4];
#pragma unroll
  for (int r = 0; r < 4; ++r){
    lAt[r] = __shfl(lA, lrow*4 + r);
    lBt[r] = __shfl(lB, lrow*4 + r);
  }
#pragma unroll
  for (int r = 0; r < 4; ++r){
    const float invA = 1.f / lAt[r];
    const float invB = 1.f / lBt[r];
    ushort* oa = out + ((size_t)b*Ssz + qtA*64 + wave*16 + lrow*4 + r)*Hsz + h*HDd;
    ushort* ob = out + ((size_t)b*Ssz + qtB*64 + wave*16 + lrow*4 + r)*Hsz + h*HDd;
#pragma unroll
    for (int dt = 0; dt < 8; ++dt){
      oa[dt*16 + lcol] = f2bf(accA[dt][r] * invA);
      ob[dt*16 + lcol] = f2bf(accB[dt][r] * invB);
    }
  }
}

extern "C" void kernel_launch(void* const* d_in, const int* in_sizes, int n_in,
                              void* d_out, int out_size, void* d_ws, size_t ws_size,
                              hipStream_t stream){
  (void)in_sizes; (void)n_in; (void)out_size;
  const float* hs  = (const float*)d_in[0];
  // d_in[1] = attention_mask: exactly causal 0/-1e9, applied analytically in k_attn
  const int*   pos = (const int*)  d_in[2];
  const float* Wq  = (const float*)d_in[3];
  const float* bq  = (const float*)d_in[4];
  const float* Wk  = (const float*)d_in[5];
  const float* bk  = (const float*)d_in[6];
  const float* Wv  = (const float*)d_in[7];
  const float* bv  = (const float*)d_in[8];
  const float* Wo  = (const float*)d_in[9];

  if (ws_size < 59779072) return;  // need ~57 MB scratch

  char* ws = (char*)d_ws;
  ushort* Xbf   = (ushort*)(ws + 0);          // 16,777,216 B; reused as attn output
  ushort* WqkvT = (ushort*)(ws + 16777216);   // 10,485,760 B (2560 x 2048 bf16)
  ushort* WoT   = (ushort*)(ws + 27262976);   //  8,388,608 B
  float*  bqkv  = (float*) (ws + 35651584);   //     10,240 B
  float*  cosb  = (float*) (ws + 35661824);   //    524,288 B
  float*  sinb  = (float*) (ws + 36186112);   //    524,288 B
  ushort* qkv   = (ushort*)(ws + 36710400);   // 20,971,520 B (4096 x 2560 bf16)
  ushort* vt    = (ushort*)(ws + 57681920);   //  2,097,152 B
  ushort* attn  = Xbf;

  k_convert  <<<8192, 256, 0, stream>>>(hs, Xbf);
  k_transpose<<<dim3(64,64), dim3(32,8), 0, stream>>>(Wq, WqkvT, 2048, 0);
  k_transpose<<<dim3(64, 8), dim3(32,8), 0, stream>>>(Wk, WqkvT, 256, 2048);
  k_transpose<<<dim3(64, 8), dim3(32,8), 0, stream>>>(Wv, WqkvT, 256, 2304);
  k_transpose<<<dim3(64,64), dim3(32,8), 0, stream>>>(Wo, WoT, 2048, 0);
  k_bias     <<<10, 256, 0, stream>>>(bq, bk, bv, bqkv);
  k_ropetab  <<<2048, 64, 0, stream>>>(pos, cosb, sinb);
  k_gemm<true,  true ><<<dim3(32,20), 256, 0, stream>>>(Xbf, WqkvT, bqkv, qkv, 2560, 2048);
  k_rope     <<<dim3(2048,2), 256, 0, stream>>>(qkv, cosb, sinb);
  k_vt       <<<dim3(32,2,4), 256, 0, stream>>>(qkv, vt);
  k_attn     <<<dim3(16,16,2), 256, 0, stream>>>(qkv, vt, attn);
  k_gemm<false, false><<<dim3(32,16), 256, 0, stream>>>(attn, WoT, nullptr, d_out, 2048, 2048);
}

// Round 4
// 327.789 us; speedup vs baseline: 1.2871x; 1.2871x over previous
//
#include <hip/hip_runtime.h>
#include <stdint.h>

// Problem constants (B,S,H)=(2,2048,2048), NH=16, NKV=2, HD=128, theta=1e6
#define Bsz  2
#define Ssz  2048
#define Hsz  2048
#define NHh  16
#define NKVh 2
#define HDd  128
#define NQKV 2560   // H + 2*KV = 2048 + 512

typedef __attribute__((ext_vector_type(8))) short bfrag;  // 8 x bf16 (4 VGPRs)
typedef __attribute__((ext_vector_type(4))) float facc;   // MFMA f32 accum

#define AS1 __attribute__((address_space(1)))
#define AS3 __attribute__((address_space(3)))

__device__ __forceinline__ ushort f2bf(float x){
  union { float f; uint32_t u; } v; v.f = x;
  return (ushort)((v.u + 0x7fffu + ((v.u >> 16) & 1u)) >> 16);
}
__device__ __forceinline__ float bf2f(ushort x){
  union { uint32_t u; float f; } v; v.u = ((uint32_t)x) << 16; return v.f;
}

// ---- fp32 -> bf16 bulk convert (X) ----
__global__ void k_convert(const float* __restrict__ in, ushort* __restrict__ out){
  const size_t i = ((size_t)blockIdx.x * 256 + threadIdx.x) * 4;
  const float4 v = *(const float4*)(in + i);
  ushort4 o;
  o.x = f2bf(v.x); o.y = f2bf(v.y); o.z = f2bf(v.z); o.w = f2bf(v.w);
  *(ushort4*)(out + i) = o;
}

// ---- transpose-convert: in (2048 x N) f32 row-major -> out bf16 rows (rowoff+n), ld 2048 ----
__global__ void k_transpose(const float* __restrict__ in, ushort* __restrict__ out,
                            int N, int rowoff){
  __shared__ float t[32][33];
  const int k0 = blockIdx.x * 32, n0 = blockIdx.y * 32;
  const int tx = threadIdx.x, ty = threadIdx.y; // 32 x 8
#pragma unroll
  for (int i = 0; i < 4; ++i)
    t[ty + i*8][tx] = in[(size_t)(k0 + ty + i*8) * N + n0 + tx];
  __syncthreads();
#pragma unroll
  for (int i = 0; i < 4; ++i)
    out[(size_t)(rowoff + n0 + ty + i*8) * 2048 + k0 + tx] = f2bf(t[tx][ty + i*8]);
}

// ---- concat biases (fp32) ----
__global__ void k_bias(const float* __restrict__ bq, const float* __restrict__ bk,
                       const float* __restrict__ bv, float* __restrict__ o){
  const int i = blockIdx.x * 256 + threadIdx.x;
  if (i < 2048)      o[i] = bq[i];
  else if (i < 2304) o[i] = bk[i - 2048];
  else if (i < 2560) o[i] = bv[i - 2304];
}

// ---- RoPE cos/sin table from position_ids ----
__global__ void k_ropetab(const int* __restrict__ pos, float* __restrict__ cosb,
                          float* __restrict__ sinb){
  const int s = blockIdx.x, j = threadIdx.x; // 64 threads
  const float p = (float)pos[s];
  const float fr = expf(-(float)j * (13.815510557964274f / 64.f)); // 1/theta^(j/64)
  const float t = p * fr;
  cosb[s*64 + j] = cosf(t);
  sinb[s*64 + j] = sinf(t);
}

// ---- m97-structure bf16 GEMM: C[M,N] = A[M,K] * Bt[N,K]^T (+bias) ----
template<bool HAS_BIAS, bool OUT_BF16>
__global__ __launch_bounds__(256) void k_gemm(const ushort* __restrict__ A,
                                              const ushort* __restrict__ Bt,
                                              const float* __restrict__ bias,
                                              void* __restrict__ Cout, int N, int K){
  __shared__ ushort As[128*64];
  __shared__ ushort Bs[128*64];
  const int m0 = blockIdx.x * 128;
  const int n0 = blockIdx.y * 128;
  const int tid = threadIdx.x;
  const int wave = tid >> 6, lane = tid & 63;
  const int wm = wave >> 1, wn = wave & 1;
  const int lrow = lane >> 4, lcol = lane & 15;
  const int srow = lane >> 3;          // 0..7 rows within a 1KB chunk
  const int scol = (lane & 7) * 8;     // element offset within 64-elem k-slice
  facc acc[4][4] = {};
  for (int k0 = 0; k0 < K; k0 += 64){
#pragma unroll
    for (int i = 0; i < 8; ++i){
      const int c = wave*8 + i;        // 0..31; <16 = A chunks, else B chunks
      if (c < 16){
        const ushort* g = A + (size_t)(m0 + c*8 + srow) * K + k0 + scol;
        __builtin_amdgcn_global_load_lds((const AS1 void*)g, (AS3 void*)(As + c*512), 16, 0, 0);
      } else {
        const ushort* g = Bt + (size_t)(n0 + (c-16)*8 + srow) * K + k0 + scol;
        __builtin_amdgcn_global_load_lds((const AS1 void*)g, (AS3 void*)(Bs + (c-16)*512), 16, 0, 0);
      }
    }
    __syncthreads();
#pragma unroll
    for (int kk = 0; kk < 2; ++kk){
      bfrag af[4], bf[4];
#pragma unroll
      for (int mi = 0; mi < 4; ++mi)
        af[mi] = *(const bfrag*)(As + (wm*64 + mi*16 + lcol)*64 + kk*32 + lrow*8);
#pragma unroll
      for (int ni = 0; ni < 4; ++ni)
        bf[ni] = *(const bfrag*)(Bs + (wn*64 + ni*16 + lcol)*64 + kk*32 + lrow*8);
#pragma unroll
      for (int mi = 0; mi < 4; ++mi)
#pragma unroll
        for (int ni = 0; ni < 4; ++ni)
          acc[mi][ni] = __builtin_amdgcn_mfma_f32_16x16x32_bf16(af[mi], bf[ni], acc[mi][ni], 0, 0, 0);
    }
    __syncthreads();
  }
#pragma unroll
  for (int mi = 0; mi < 4; ++mi){
#pragma unroll
    for (int ni = 0; ni < 4; ++ni){
      const int col = n0 + wn*64 + ni*16 + lcol;
      const float bsv = HAS_BIAS ? bias[col] : 0.f;
#pragma unroll
      for (int r = 0; r < 4; ++r){
        const size_t row = (size_t)m0 + wm*64 + mi*16 + lrow*4 + r;
        const float v = acc[mi][ni][r] + bsv;
        if (OUT_BF16) ((ushort*)Cout)[row * N + col] = f2bf(v);
        else          ((float*) Cout)[row * N + col] = v;
      }
    }
  }
}

// ---- in-place RoPE on q (cols 0..2047) and k (cols 2048..2303) of qkv ----
__global__ void k_rope(ushort* __restrict__ qkv, const float* __restrict__ cosb,
                       const float* __restrict__ sinb){
  const int s = blockIdx.x, b = blockIdx.y;
  ushort* rp = qkv + ((size_t)(b*Ssz + s)) * NQKV;
  const float* cb = cosb + s*64;
  const float* sb = sinb + s*64;
  for (int i = threadIdx.x; i < 18*64; i += 256){  // 16 q-heads + 2 kv-heads
    const int hh = i >> 6, d = i & 63;
    ushort* p = rp + hh*128 + d;
    const float x1 = bf2f(p[0]), x2 = bf2f(p[64]);
    const float c = cb[d], sn = sb[d];
    p[0]  = f2bf(x1*c  - x2*sn);
    p[64] = f2bf(x1*sn + x2*c);
  }
}

// ---- V relayout: qkv cols [2304,2560) (b,s,kv,d) -> vt (b,kv,d,s) ----
__global__ void k_vt(const ushort* __restrict__ qkv, ushort* __restrict__ vt){
  __shared__ ushort t[64][65];
  const int s0 = blockIdx.x * 64, d0 = blockIdx.y * 64;
  const int bkv = blockIdx.z, b = bkv >> 1, kv = bkv & 1;
  for (int i = threadIdx.x; i < 4096; i += 256){
    const int sl = i >> 6, dl = i & 63;
    t[sl][dl] = qkv[(size_t)(b*Ssz + s0 + sl)*NQKV + 2304 + kv*128 + d0 + dl];
  }
  __syncthreads();
  for (int i = threadIdx.x; i < 4096; i += 256){
    const int dl = i >> 6, sl = i & 63;
    vt[((size_t)(bkv*128 + d0 + dl))*Ssz + s0 + sl] = t[sl][dl];
  }
}

// ---- causal GQA flash attention, paired q-tiles + K dbuf via global_load_lds ----
// Round-2 proven step structure (mfma(Q,K), per-row shfl softmax). New: K tile is
// double-buffered, staged by global_load_lds DMA with XOR-swizzled source (rule #21);
// V reg-split staged (T14); launch_bounds(256,2) so staging regs never spill.
__global__ __launch_bounds__(256, 2) void k_attn(const ushort* __restrict__ qkv,
                                                 const ushort* __restrict__ vt,
                                                 ushort* __restrict__ out){
  __shared__ __attribute__((aligned(16))) char klds2[2*16384];  // K dbuf, 64 rows x 256B, swizzled
  __shared__ __attribute__((aligned(16))) char vlds[128*144];   // V^T 128 x (64 bf16 + 16B pad)
  __shared__ __attribute__((aligned(16))) char plds[4*2304];    // per-wave P 16 x (64 bf16 + pad)
  const int p = blockIdx.x, h = blockIdx.y, b = blockIdx.z;
  const int qtA = p, qtB = 31 - p;
  const int kvh = h >> 3;                 // rep = NH/NKV = 8
  const int tid = threadIdx.x, wave = tid >> 6, lane = tid & 63;
  const int lrow = lane >> 4, lcol = lane & 15;

  bfrag qfA[4], qfB[4];
  {
    const ushort* qa = qkv + ((size_t)b*Ssz + qtA*64 + wave*16 + lcol)*NQKV + h*HDd + lrow*8;
    const ushort* qb = qkv + ((size_t)b*Ssz + qtB*64 + wave*16 + lcol)*NQKV + h*HDd + lrow*8;
#pragma unroll
    for (int kk = 0; kk < 4; ++kk){
      qfA[kk] = *(const bfrag*)(qa + kk*32);
      qfB[kk] = *(const bfrag*)(qb + kk*32);
    }
  }
  facc accA[8] = {}, accB[8] = {};
  float mA[4], lA[4], mB[4], lB[4];
#pragma unroll
  for (int r = 0; r < 4; ++r){ mA[r] = -1e30f; lA[r] = 0.f; mB[r] = -1e30f; lB[r] = 0.f; }

  const ushort* kb = qkv + (size_t)b*Ssz*NQKV + Hsz + kvh*HDd;
  const ushort* vb = vt + ((size_t)(b*NKVh + kvh))*HDd*Ssz;
  char* pw = plds + wave*2304;            // single P buffer per wave (in-order DS => safe)

  // K tile t -> dst (linear LDS, 64 rows x 256B) via global_load_lds DMA.
  // LDS slot (row, cb) holds K[row][cb ^ ((row&7)<<4)] (pre-swizzled source).
  auto issueK = [&](int t, char* dst){
    const ushort* kt = kb + (size_t)t*64*NQKV;
#pragma unroll
    for (int i = 0; i < 4; ++i){
      const int row = i*16 + wave*4 + (lane >> 4);   // this lane's row in the tile
      const int cb  = (lane & 15) * 16;              // this lane's 16B column slot
      const char* g = (const char*)(kt + (size_t)row*NQKV) + (cb ^ ((row & 7) << 4));
      __builtin_amdgcn_global_load_lds((const AS1 void*)g,
          (AS3 void*)(dst + i*4096 + wave*1024), 16, 0, 0);
    }
  };

  int4 vreg[4];                           // V staging registers (T14 split)
  auto loadV = [&](int t){
#pragma unroll
    for (int i = 0; i < 4; ++i){
      const int c = tid + 256*i;
      vreg[i] = *(const int4*)((const char*)(vb + (size_t)(c>>3)*Ssz + t*64) + (c&7)*16);
    }
  };
  auto writeV = [&](){
#pragma unroll
    for (int i = 0; i < 4; ++i){
      const int c = tid + 256*i;
      *(int4*)(vlds + (c>>3)*144 + (c&7)*16) = vreg[i];
    }
  };

  // one tile-step (round-2 structure): QK^T -> online softmax -> P pack -> PV
  auto step = [&](int t, int qx, bfrag* qf, facc* acc, float* mrow, float* lsum,
                  const char* kcur){
    facc sc[4] = {};
#pragma unroll
    for (int kk = 0; kk < 4; ++kk){        // QK^T: 16 MFMA, swizzled K reads
#pragma unroll
      for (int nt = 0; nt < 4; ++nt){
        const bfrag kf = *(const bfrag*)(kcur + (nt*16 + lcol)*256 +
                                         ((kk*64 + lrow*16) ^ ((lcol & 7) << 4)));
        sc[nt] = __builtin_amdgcn_mfma_f32_16x16x32_bf16(qf[kk], kf, sc[nt], 0, 0, 0);
      }
    }
    const bool diag = (t == qx);
    float pv[4][4];
#pragma unroll
    for (int nt = 0; nt < 4; ++nt){
      const int kg = t*64 + nt*16 + lcol;
#pragma unroll
      for (int r = 0; r < 4; ++r){
        float sv = sc[nt][r] * 0.088388347648318447f;  // 1/sqrt(128)
        if (diag && kg > qx*64 + wave*16 + lrow*4 + r) sv = -1e30f;
        pv[nt][r] = sv;
      }
    }
#pragma unroll
    for (int r = 0; r < 4; ++r){           // online softmax, per q-row
      float mx = fmaxf(fmaxf(pv[0][r], pv[1][r]), fmaxf(pv[2][r], pv[3][r]));
      mx = fmaxf(mx, __shfl_xor(mx, 1));
      mx = fmaxf(mx, __shfl_xor(mx, 2));
      mx = fmaxf(mx, __shfl_xor(mx, 4));
      mx = fmaxf(mx, __shfl_xor(mx, 8));
      const float mn = fmaxf(mrow[r], mx);
      const float corr = __expf(mrow[r] - mn);
      float rs = 0.f;
#pragma unroll
      for (int nt = 0; nt < 4; ++nt){
        const float e = __expf(pv[nt][r] - mn);
        pv[nt][r] = e; rs += e;
      }
      rs += __shfl_xor(rs, 1);
      rs += __shfl_xor(rs, 2);
      rs += __shfl_xor(rs, 4);
      rs += __shfl_xor(rs, 8);
      lsum[r] = lsum[r]*corr + rs;
      mrow[r] = mn;
#pragma unroll
      for (int dt = 0; dt < 8; ++dt) acc[dt][r] *= corr;
    }
#pragma unroll
    for (int nt = 0; nt < 4; ++nt)         // P -> per-wave LDS (bf16)
#pragma unroll
      for (int r = 0; r < 4; ++r)
        *(ushort*)(pw + (lrow*4 + r)*144 + (nt*16 + lcol)*2) = f2bf(pv[nt][r]);
    asm volatile("s_waitcnt lgkmcnt(0)" ::: "memory");
#pragma unroll
    for (int kk2 = 0; kk2 < 2; ++kk2){     // PV: 16 MFMA
      const bfrag pa = *(const bfrag*)(pw + lcol*144 + kk2*64 + lrow*16);
#pragma unroll
      for (int dt = 0; dt < 8; ++dt){
        const bfrag vf = *(const bfrag*)(vlds + (dt*16 + lcol)*144 + kk2*64 + lrow*16);
        acc[dt] = __builtin_amdgcn_mfma_f32_16x16x32_bf16(pa, vf, acc[dt], 0, 0, 0);
      }
    }
  };

  // prologue: tile 0
  issueK(0, klds2);
  loadV(0);
  writeV();
  __syncthreads();                         // drains K DMA (vmcnt) + V writes (lgkm)

  int cur = 0;
  for (int t = 0; t <= qtB; ++t){
    const bool more = (t < qtB);
    if (more){
      issueK(t + 1, klds2 + (cur ^ 1)*16384);  // DMA next K tile into other buffer
      loadV(t + 1);                            // V loads in flight under compute
    }
    const char* kcur = klds2 + cur*16384;
    step(t, qtB, qfB, accB, mB, lB, kcur);
    if (t <= qtA) step(t, qtA, qfA, accA, mA, lA, kcur);
    __syncthreads();                       // all reads done; K DMA + V loads drained here
    if (more) writeV();
    __syncthreads();                       // vlds(t+1) visible to all waves
    cur ^= 1;
  }

#pragma unroll
  for (int r = 0; r < 4; ++r){
    const float invA = 1.f / lA[r];
    const float invB = 1.f / lB[r];
    ushort* oa = out + ((size_t)b*Ssz + qtA*64 + wave*16 + lrow*4 + r)*Hsz + h*HDd;
    ushort* ob = out + ((size_t)b*Ssz + qtB*64 + wave*16 + lrow*4 + r)*Hsz + h*HDd;
#pragma unroll
    for (int dt = 0; dt < 8; ++dt){
      oa[dt*16 + lcol] = f2bf(accA[dt][r] * invA);
      ob[dt*16 + lcol] = f2bf(accB[dt][r] * invB);
    }
  }
}

extern "C" void kernel_launch(void* const* d_in, const int* in_sizes, int n_in,
                              void* d_out, int out_size, void* d_ws, size_t ws_size,
                              hipStream_t stream){
  (void)in_sizes; (void)n_in; (void)out_size;
  const float* hs  = (const float*)d_in[0];
  // d_in[1] = attention_mask: exactly causal 0/-1e9, applied analytically in k_attn
  const int*   pos = (const int*)  d_in[2];
  const float* Wq  = (const float*)d_in[3];
  const float* bq  = (const float*)d_in[4];
  const float* Wk  = (const float*)d_in[5];
  const float* bk  = (const float*)d_in[6];
  const float* Wv  = (const float*)d_in[7];
  const float* bv  = (const float*)d_in[8];
  const float* Wo  = (const float*)d_in[9];

  if (ws_size < 59779072) return;  // need ~57 MB scratch

  char* ws = (char*)d_ws;
  ushort* Xbf   = (ushort*)(ws + 0);          // 16,777,216 B; reused as attn output
  ushort* WqkvT = (ushort*)(ws + 16777216);   // 10,485,760 B (2560 x 2048 bf16)
  ushort* WoT   = (ushort*)(ws + 27262976);   //  8,388,608 B
  float*  bqkv  = (float*) (ws + 35651584);   //     10,240 B
  float*  cosb  = (float*) (ws + 35661824);   //    524,288 B
  float*  sinb  = (float*) (ws + 36186112);   //    524,288 B
  ushort* qkv   = (ushort*)(ws + 36710400);   // 20,971,520 B (4096 x 2560 bf16)
  ushort* vt    = (ushort*)(ws + 57681920);   //  2,097,152 B
  ushort* attn  = Xbf;

  k_convert  <<<8192, 256, 0, stream>>>(hs, Xbf);
  k_transpose<<<dim3(64,64), dim3(32,8), 0, stream>>>(Wq, WqkvT, 2048, 0);
  k_transpose<<<dim3(64, 8), dim3(32,8), 0, stream>>>(Wk, WqkvT, 256, 2048);
  k_transpose<<<dim3(64, 8), dim3(32,8), 0, stream>>>(Wv, WqkvT, 256, 2304);
  k_transpose<<<dim3(64,64), dim3(32,8), 0, stream>>>(Wo, WoT, 2048, 0);
  k_bias     <<<10, 256, 0, stream>>>(bq, bk, bv, bqkv);
  k_ropetab  <<<2048, 64, 0, stream>>>(pos, cosb, sinb);
  k_gemm<true,  true ><<<dim3(32,20), 256, 0, stream>>>(Xbf, WqkvT, bqkv, qkv, 2560, 2048);
  k_rope     <<<dim3(2048,2), 256, 0, stream>>>(qkv, cosb, sinb);
  k_vt       <<<dim3(32,2,4), 256, 0, stream>>>(qkv, vt);
  k_attn     <<<dim3(16,16,2), 256, 0, stream>>>(qkv, vt, attn);
  k_gemm<false, false><<<dim3(32,16), 256, 0, stream>>>(attn, WoT, nullptr, d_out, 2048, 2048);
}

// Round 5
// 316.371 us; speedup vs baseline: 1.3335x; 1.0361x over previous
//
#include <hip/hip_runtime.h>
#include <stdint.h>

// Problem constants (B,S,H)=(2,2048,2048), NH=16, NKV=2, HD=128, theta=1e6
#define Bsz  2
#define Ssz  2048
#define Hsz  2048
#define NHh  16
#define NKVh 2
#define HDd  128
#define NQKV 2560   // H + 2*KV = 2048 + 512

typedef __attribute__((ext_vector_type(8))) short bfrag;  // 8 x bf16 (4 VGPRs)
typedef __attribute__((ext_vector_type(4))) float facc;   // MFMA f32 accum

#define AS1 __attribute__((address_space(1)))
#define AS3 __attribute__((address_space(3)))

__device__ __forceinline__ ushort f2bf(float x){
  union { float f; uint32_t u; } v; v.f = x;
  return (ushort)((v.u + 0x7fffu + ((v.u >> 16) & 1u)) >> 16);
}
__device__ __forceinline__ float bf2f(ushort x){
  union { uint32_t u; float f; } v; v.u = ((uint32_t)x) << 16; return v.f;
}

// ---- fp32 -> bf16 bulk convert (X) ----
__global__ void k_convert(const float* __restrict__ in, ushort* __restrict__ out){
  const size_t i = ((size_t)blockIdx.x * 256 + threadIdx.x) * 4;
  const float4 v = *(const float4*)(in + i);
  ushort4 o;
  o.x = f2bf(v.x); o.y = f2bf(v.y); o.z = f2bf(v.z); o.w = f2bf(v.w);
  *(ushort4*)(out + i) = o;
}

// ---- transpose-convert: in (2048 x N) f32 row-major -> out bf16 rows (rowoff+n), ld 2048 ----
__global__ void k_transpose(const float* __restrict__ in, ushort* __restrict__ out,
                            int N, int rowoff){
  __shared__ float t[32][33];
  const int k0 = blockIdx.x * 32, n0 = blockIdx.y * 32;
  const int tx = threadIdx.x, ty = threadIdx.y; // 32 x 8
#pragma unroll
  for (int i = 0; i < 4; ++i)
    t[ty + i*8][tx] = in[(size_t)(k0 + ty + i*8) * N + n0 + tx];
  __syncthreads();
#pragma unroll
  for (int i = 0; i < 4; ++i)
    out[(size_t)(rowoff + n0 + ty + i*8) * 2048 + k0 + tx] = f2bf(t[tx][ty + i*8]);
}

// ---- concat biases (fp32) ----
__global__ void k_bias(const float* __restrict__ bq, const float* __restrict__ bk,
                       const float* __restrict__ bv, float* __restrict__ o){
  const int i = blockIdx.x * 256 + threadIdx.x;
  if (i < 2048)      o[i] = bq[i];
  else if (i < 2304) o[i] = bk[i - 2048];
  else if (i < 2560) o[i] = bv[i - 2304];
}

// ---- RoPE cos/sin table from position_ids ----
__global__ void k_ropetab(const int* __restrict__ pos, float* __restrict__ cosb,
                          float* __restrict__ sinb){
  const int s = blockIdx.x, j = threadIdx.x; // 64 threads
  const float p = (float)pos[s];
  const float fr = expf(-(float)j * (13.815510557964274f / 64.f)); // 1/theta^(j/64)
  const float t = p * fr;
  cosb[s*64 + j] = cosf(t);
  sinb[s*64 + j] = sinf(t);
}

// ---- m97-structure bf16 GEMM: C[M,N] = A[M,K] * Bt[N,K]^T (+bias) ----
template<bool HAS_BIAS, bool OUT_BF16>
__global__ __launch_bounds__(256) void k_gemm(const ushort* __restrict__ A,
                                              const ushort* __restrict__ Bt,
                                              const float* __restrict__ bias,
                                              void* __restrict__ Cout, int N, int K){
  __shared__ ushort As[128*64];
  __shared__ ushort Bs[128*64];
  const int m0 = blockIdx.x * 128;
  const int n0 = blockIdx.y * 128;
  const int tid = threadIdx.x;
  const int wave = tid >> 6, lane = tid & 63;
  const int wm = wave >> 1, wn = wave & 1;
  const int lrow = lane >> 4, lcol = lane & 15;
  const int srow = lane >> 3;          // 0..7 rows within a 1KB chunk
  const int scol = (lane & 7) * 8;     // element offset within 64-elem k-slice
  facc acc[4][4] = {};
  for (int k0 = 0; k0 < K; k0 += 64){
#pragma unroll
    for (int i = 0; i < 8; ++i){
      const int c = wave*8 + i;        // 0..31; <16 = A chunks, else B chunks
      if (c < 16){
        const ushort* g = A + (size_t)(m0 + c*8 + srow) * K + k0 + scol;
        __builtin_amdgcn_global_load_lds((const AS1 void*)g, (AS3 void*)(As + c*512), 16, 0, 0);
      } else {
        const ushort* g = Bt + (size_t)(n0 + (c-16)*8 + srow) * K + k0 + scol;
        __builtin_amdgcn_global_load_lds((const AS1 void*)g, (AS3 void*)(Bs + (c-16)*512), 16, 0, 0);
      }
    }
    __syncthreads();
#pragma unroll
    for (int kk = 0; kk < 2; ++kk){
      bfrag af[4], bf[4];
#pragma unroll
      for (int mi = 0; mi < 4; ++mi)
        af[mi] = *(const bfrag*)(As + (wm*64 + mi*16 + lcol)*64 + kk*32 + lrow*8);
#pragma unroll
      for (int ni = 0; ni < 4; ++ni)
        bf[ni] = *(const bfrag*)(Bs + (wn*64 + ni*16 + lcol)*64 + kk*32 + lrow*8);
#pragma unroll
      for (int mi = 0; mi < 4; ++mi)
#pragma unroll
        for (int ni = 0; ni < 4; ++ni)
          acc[mi][ni] = __builtin_amdgcn_mfma_f32_16x16x32_bf16(af[mi], bf[ni], acc[mi][ni], 0, 0, 0);
    }
    __syncthreads();
  }
#pragma unroll
  for (int mi = 0; mi < 4; ++mi){
#pragma unroll
    for (int ni = 0; ni < 4; ++ni){
      const int col = n0 + wn*64 + ni*16 + lcol;
      const float bsv = HAS_BIAS ? bias[col] : 0.f;
#pragma unroll
      for (int r = 0; r < 4; ++r){
        const size_t row = (size_t)m0 + wm*64 + mi*16 + lrow*4 + r;
        const float v = acc[mi][ni][r] + bsv;
        if (OUT_BF16) ((ushort*)Cout)[row * N + col] = f2bf(v);
        else          ((float*) Cout)[row * N + col] = v;
      }
    }
  }
}

// ---- in-place RoPE on q (cols 0..2047) and k (cols 2048..2303) of qkv ----
__global__ void k_rope(ushort* __restrict__ qkv, const float* __restrict__ cosb,
                       const float* __restrict__ sinb){
  const int s = blockIdx.x, b = blockIdx.y;
  ushort* rp = qkv + ((size_t)(b*Ssz + s)) * NQKV;
  const float* cb = cosb + s*64;
  const float* sb = sinb + s*64;
  for (int i = threadIdx.x; i < 18*64; i += 256){  // 16 q-heads + 2 kv-heads
    const int hh = i >> 6, d = i & 63;
    ushort* p = rp + hh*128 + d;
    const float x1 = bf2f(p[0]), x2 = bf2f(p[64]);
    const float c = cb[d], sn = sb[d];
    p[0]  = f2bf(x1*c  - x2*sn);
    p[64] = f2bf(x1*sn + x2*c);
  }
}

// ---- V relayout: qkv cols [2304,2560) (b,s,kv,d) -> vt (b,kv,d,s) ----
__global__ void k_vt(const ushort* __restrict__ qkv, ushort* __restrict__ vt){
  __shared__ ushort t[64][65];
  const int s0 = blockIdx.x * 64, d0 = blockIdx.y * 64;
  const int bkv = blockIdx.z, b = bkv >> 1, kv = bkv & 1;
  for (int i = threadIdx.x; i < 4096; i += 256){
    const int sl = i >> 6, dl = i & 63;
    t[sl][dl] = qkv[(size_t)(b*Ssz + s0 + sl)*NQKV + 2304 + kv*128 + d0 + dl];
  }
  __syncthreads();
  for (int i = threadIdx.x; i < 4096; i += 256){
    const int dl = i >> 6, sl = i & 63;
    vt[((size_t)(bkv*128 + d0 + dl))*Ssz + s0 + sl] = t[sl][dl];
  }
}

// ---- causal GQA flash attention, 8-wave blocks: groups compute paired q-tiles ----
// Waves 0-3 -> q-tile B=31-p (long), waves 4-7 -> q-tile A=p (short), CONCURRENTLY.
// 512 thr x 512 blocks = 2 blocks/CU = 16 waves/CU (4/SIMD) for latency hiding.
// K double-buffered via global_load_lds DMA with XOR-swizzled source (rule #21);
// V reg-split staged (T14). launch_bounds(512,4) caps VGPR at 128 (no spill).
__global__ __launch_bounds__(512, 4) void k_attn(const ushort* __restrict__ qkv,
                                                 const ushort* __restrict__ vt,
                                                 ushort* __restrict__ out){
  __shared__ __attribute__((aligned(16))) char klds2[2*16384];  // K dbuf, 64 rows x 256B, swizzled
  __shared__ __attribute__((aligned(16))) char vlds[128*144];   // V^T 128 x (64 bf16 + 16B pad)
  __shared__ __attribute__((aligned(16))) char plds[8*2304];    // per-wave P 16 x (64 bf16 + pad)
  const int p = blockIdx.x, h = blockIdx.y, b = blockIdx.z;
  const int qtA = p, qtB = 31 - p;                // qtB >= 16 > qtA <= 15 always
  const int kvh = h >> 3;                         // rep = NH/NKV = 8
  const int tid = threadIdx.x, wave = tid >> 6, lane = tid & 63;
  const int grp = wave >> 2, w4 = wave & 3;       // grp 0 -> tile B, grp 1 -> tile A
  const int qx = grp ? qtA : qtB;
  const int lrow = lane >> 4, lcol = lane & 15;

  bfrag qf[4];
  {
    const ushort* qp = qkv + ((size_t)b*Ssz + qx*64 + w4*16 + lcol)*NQKV + h*HDd + lrow*8;
#pragma unroll
    for (int kk = 0; kk < 4; ++kk) qf[kk] = *(const bfrag*)(qp + kk*32);
  }
  facc acc[8] = {};
  float mrow[4], lsum[4];
#pragma unroll
  for (int r = 0; r < 4; ++r){ mrow[r] = -1e30f; lsum[r] = 0.f; }

  const ushort* kb = qkv + (size_t)b*Ssz*NQKV + Hsz + kvh*HDd;
  const ushort* vb = vt + ((size_t)(b*NKVh + kvh))*HDd*Ssz;
  char* pw = plds + wave*2304;

  // K tile t -> dst via global_load_lds DMA; LDS slot (row,cb) holds
  // K[row][cb ^ ((row&7)<<4)] (pre-swizzled source, linear dest).
  auto issueK = [&](int t, char* dst){
    const ushort* kt = kb + (size_t)t*64*NQKV;
#pragma unroll
    for (int i = 0; i < 2; ++i){
      const int row = i*32 + wave*4 + (lane >> 4);
      const int cb  = (lane & 15) * 16;
      const char* g = (const char*)(kt + (size_t)row*NQKV) + (cb ^ ((row & 7) << 4));
      __builtin_amdgcn_global_load_lds((const AS1 void*)g,
          (AS3 void*)(dst + i*8192 + wave*1024), 16, 0, 0);
    }
  };

  int4 vreg[2];                          // V staging registers (T14 split)
  auto loadV = [&](int t){
#pragma unroll
    for (int i = 0; i < 2; ++i){
      const int c = i*512 + tid;
      vreg[i] = *(const int4*)((const char*)(vb + (size_t)(c>>3)*Ssz + t*64) + (c&7)*16);
    }
  };
  auto writeV = [&](){
#pragma unroll
    for (int i = 0; i < 2; ++i){
      const int c = i*512 + tid;
      *(int4*)(vlds + (c>>3)*144 + (c&7)*16) = vreg[i];
    }
  };

  // one tile-step: QK^T -> online softmax -> P pack -> PV (this wave's 16 q-rows)
  auto step = [&](int t, const char* kcur){
    facc sc[4] = {};
#pragma unroll
    for (int kk = 0; kk < 4; ++kk){        // QK^T: 16 MFMA, swizzled K reads
#pragma unroll
      for (int nt = 0; nt < 4; ++nt){
        const bfrag kf = *(const bfrag*)(kcur + (nt*16 + lcol)*256 +
                                         ((kk*64 + lrow*16) ^ ((lcol & 7) << 4)));
        sc[nt] = __builtin_amdgcn_mfma_f32_16x16x32_bf16(qf[kk], kf, sc[nt], 0, 0, 0);
      }
    }
    const bool diag = (t == qx);
    float pv[4][4];
#pragma unroll
    for (int nt = 0; nt < 4; ++nt){
      const int kg = t*64 + nt*16 + lcol;
#pragma unroll
      for (int r = 0; r < 4; ++r){
        float sv = sc[nt][r] * 0.088388347648318447f;  // 1/sqrt(128)
        if (diag && kg > qx*64 + w4*16 + lrow*4 + r) sv = -1e30f;
        pv[nt][r] = sv;
      }
    }
#pragma unroll
    for (int r = 0; r < 4; ++r){           // online softmax, per q-row
      float mx = fmaxf(fmaxf(pv[0][r], pv[1][r]), fmaxf(pv[2][r], pv[3][r]));
      mx = fmaxf(mx, __shfl_xor(mx, 1));
      mx = fmaxf(mx, __shfl_xor(mx, 2));
      mx = fmaxf(mx, __shfl_xor(mx, 4));
      mx = fmaxf(mx, __shfl_xor(mx, 8));
      const float mn = fmaxf(mrow[r], mx);
      const float corr = __expf(mrow[r] - mn);
      float rs = 0.f;
#pragma unroll
      for (int nt = 0; nt < 4; ++nt){
        const float e = __expf(pv[nt][r] - mn);
        pv[nt][r] = e; rs += e;
      }
      rs += __shfl_xor(rs, 1);
      rs += __shfl_xor(rs, 2);
      rs += __shfl_xor(rs, 4);
      rs += __shfl_xor(rs, 8);
      lsum[r] = lsum[r]*corr + rs;
      mrow[r] = mn;
#pragma unroll
      for (int dt = 0; dt < 8; ++dt) acc[dt][r] *= corr;
    }
#pragma unroll
    for (int nt = 0; nt < 4; ++nt)         // P -> per-wave LDS (bf16)
#pragma unroll
      for (int r = 0; r < 4; ++r)
        *(ushort*)(pw + (lrow*4 + r)*144 + (nt*16 + lcol)*2) = f2bf(pv[nt][r]);
    asm volatile("s_waitcnt lgkmcnt(0)" ::: "memory");
#pragma unroll
    for (int kk2 = 0; kk2 < 2; ++kk2){     // PV: 16 MFMA
      const bfrag pa = *(const bfrag*)(pw + lcol*144 + kk2*64 + lrow*16);
#pragma unroll
      for (int dt = 0; dt < 8; ++dt){
        const bfrag vf = *(const bfrag*)(vlds + (dt*16 + lcol)*144 + kk2*64 + lrow*16);
        acc[dt] = __builtin_amdgcn_mfma_f32_16x16x32_bf16(pa, vf, acc[dt], 0, 0, 0);
      }
    }
  };

  // prologue: tile 0
  issueK(0, klds2);
  loadV(0);
  writeV();
  __syncthreads();                         // drains K DMA (vmcnt) + V writes (lgkm)

  int cur = 0;
  for (int t = 0; t <= qtB; ++t){
    const bool more = (t < qtB);
    if (more){
      issueK(t + 1, klds2 + (cur ^ 1)*16384);  // DMA next K tile into other buffer
      loadV(t + 1);                            // V loads in flight under compute
    }
    if (t <= qx) step(t, klds2 + cur*16384);
    __syncthreads();                       // all reads done; K DMA + V loads drained
    if (more) writeV();
    __syncthreads();                       // vlds(t+1) visible to all waves
    cur ^= 1;
  }

#pragma unroll
  for (int r = 0; r < 4; ++r){
    const float inv = 1.f / lsum[r];
    ushort* op = out + ((size_t)b*Ssz + qx*64 + w4*16 + lrow*4 + r)*Hsz + h*HDd;
#pragma unroll
    for (int dt = 0; dt < 8; ++dt)
      op[dt*16 + lcol] = f2bf(acc[dt][r] * inv);
  }
}

extern "C" void kernel_launch(void* const* d_in, const int* in_sizes, int n_in,
                              void* d_out, int out_size, void* d_ws, size_t ws_size,
                              hipStream_t stream){
  (void)in_sizes; (void)n_in; (void)out_size;
  const float* hs  = (const float*)d_in[0];
  // d_in[1] = attention_mask: exactly causal 0/-1e9, applied analytically in k_attn
  const int*   pos = (const int*)  d_in[2];
  const float* Wq  = (const float*)d_in[3];
  const float* bq  = (const float*)d_in[4];
  const float* Wk  = (const float*)d_in[5];
  const float* bk  = (const float*)d_in[6];
  const float* Wv  = (const float*)d_in[7];
  const float* bv  = (const float*)d_in[8];
  const float* Wo  = (const float*)d_in[9];

  if (ws_size < 59779072) return;  // need ~57 MB scratch

  char* ws = (char*)d_ws;
  ushort* Xbf   = (ushort*)(ws + 0);          // 16,777,216 B; reused as attn output
  ushort* WqkvT = (ushort*)(ws + 16777216);   // 10,485,760 B (2560 x 2048 bf16)
  ushort* WoT   = (ushort*)(ws + 27262976);   //  8,388,608 B
  float*  bqkv  = (float*) (ws + 35651584);   //     10,240 B
  float*  cosb  = (float*) (ws + 35661824);   //    524,288 B
  float*  sinb  = (float*) (ws + 36186112);   //    524,288 B
  ushort* qkv   = (ushort*)(ws + 36710400);   // 20,971,520 B (4096 x 2560 bf16)
  ushort* vt    = (ushort*)(ws + 57681920);   //  2,097,152 B
  ushort* attn  = Xbf;

  k_convert  <<<8192, 256, 0, stream>>>(hs, Xbf);
  k_transpose<<<dim3(64,64), dim3(32,8), 0, stream>>>(Wq, WqkvT, 2048, 0);
  k_transpose<<<dim3(64, 8), dim3(32,8), 0, stream>>>(Wk, WqkvT, 256, 2048);
  k_transpose<<<dim3(64, 8), dim3(32,8), 0, stream>>>(Wv, WqkvT, 256, 2304);
  k_transpose<<<dim3(64,64), dim3(32,8), 0, stream>>>(Wo, WoT, 2048, 0);
  k_bias     <<<10, 256, 0, stream>>>(bq, bk, bv, bqkv);
  k_ropetab  <<<2048, 64, 0, stream>>>(pos, cosb, sinb);
  k_gemm<true,  true ><<<dim3(32,20), 256, 0, stream>>>(Xbf, WqkvT, bqkv, qkv, 2560, 2048);
  k_rope     <<<dim3(2048,2), 256, 0, stream>>>(qkv, cosb, sinb);
  k_vt       <<<dim3(32,2,4), 256, 0, stream>>>(qkv, vt);
  k_attn     <<<dim3(16,16,2), 512, 0, stream>>>(qkv, vt, attn);
  k_gemm<false, false><<<dim3(32,16), 256, 0, stream>>>(attn, WoT, nullptr, d_out, 2048, 2048);
}

// Round 6
// 297.323 us; speedup vs baseline: 1.4190x; 1.0641x over previous
//
#include <hip/hip_runtime.h>
#include <stdint.h>

// Problem constants (B,S,H)=(2,2048,2048), NH=16, NKV=2, HD=128, theta=1e6
#define Bsz  2
#define Ssz  2048
#define Hsz  2048
#define NHh  16
#define NKVh 2
#define HDd  128
#define NQKV 2560   // H + 2*KV = 2048 + 512

typedef __attribute__((ext_vector_type(8))) short bfrag;  // 8 x bf16 (4 VGPRs)
typedef __attribute__((ext_vector_type(4))) float facc;   // MFMA f32 accum

#define AS1 __attribute__((address_space(1)))
#define AS3 __attribute__((address_space(3)))

__device__ __forceinline__ ushort f2bf(float x){
  union { float f; uint32_t u; } v; v.f = x;
  return (ushort)((v.u + 0x7fffu + ((v.u >> 16) & 1u)) >> 16);
}
__device__ __forceinline__ float bf2f(ushort x){
  union { uint32_t u; float f; } v; v.u = ((uint32_t)x) << 16; return v.f;
}

// ---- fp32 -> bf16 bulk convert (X) ----
__global__ void k_convert(const float* __restrict__ in, ushort* __restrict__ out){
  const size_t i = ((size_t)blockIdx.x * 256 + threadIdx.x) * 4;
  const float4 v = *(const float4*)(in + i);
  ushort4 o;
  o.x = f2bf(v.x); o.y = f2bf(v.y); o.z = f2bf(v.z); o.w = f2bf(v.w);
  *(ushort4*)(out + i) = o;
}

// ---- transpose-convert: in (2048 x N) f32 row-major -> out bf16 rows (rowoff+n), ld 2048 ----
__global__ void k_transpose(const float* __restrict__ in, ushort* __restrict__ out,
                            int N, int rowoff){
  __shared__ float t[32][33];
  const int k0 = blockIdx.x * 32, n0 = blockIdx.y * 32;
  const int tx = threadIdx.x, ty = threadIdx.y; // 32 x 8
#pragma unroll
  for (int i = 0; i < 4; ++i)
    t[ty + i*8][tx] = in[(size_t)(k0 + ty + i*8) * N + n0 + tx];
  __syncthreads();
#pragma unroll
  for (int i = 0; i < 4; ++i)
    out[(size_t)(rowoff + n0 + ty + i*8) * 2048 + k0 + tx] = f2bf(t[tx][ty + i*8]);
}

// ---- concat biases (fp32) ----
__global__ void k_bias(const float* __restrict__ bq, const float* __restrict__ bk,
                       const float* __restrict__ bv, float* __restrict__ o){
  const int i = blockIdx.x * 256 + threadIdx.x;
  if (i < 2048)      o[i] = bq[i];
  else if (i < 2304) o[i] = bk[i - 2048];
  else if (i < 2560) o[i] = bv[i - 2304];
}

// ---- RoPE cos/sin table from position_ids ----
__global__ void k_ropetab(const int* __restrict__ pos, float* __restrict__ cosb,
                          float* __restrict__ sinb){
  const int s = blockIdx.x, j = threadIdx.x; // 64 threads
  const float p = (float)pos[s];
  const float fr = expf(-(float)j * (13.815510557964274f / 64.f)); // 1/theta^(j/64)
  const float t = p * fr;
  cosb[s*64 + j] = cosf(t);
  sinb[s*64 + j] = sinf(t);
}

// ---- m97-structure bf16 GEMM: C[M,N] = A[M,K] * Bt[N,K]^T (+bias) ----
template<bool HAS_BIAS, bool OUT_BF16>
__global__ __launch_bounds__(256) void k_gemm(const ushort* __restrict__ A,
                                              const ushort* __restrict__ Bt,
                                              const float* __restrict__ bias,
                                              void* __restrict__ Cout, int N, int K){
  __shared__ ushort As[128*64];
  __shared__ ushort Bs[128*64];
  const int m0 = blockIdx.x * 128;
  const int n0 = blockIdx.y * 128;
  const int tid = threadIdx.x;
  const int wave = tid >> 6, lane = tid & 63;
  const int wm = wave >> 1, wn = wave & 1;
  const int lrow = lane >> 4, lcol = lane & 15;
  const int srow = lane >> 3;          // 0..7 rows within a 1KB chunk
  const int scol = (lane & 7) * 8;     // element offset within 64-elem k-slice
  facc acc[4][4] = {};
  for (int k0 = 0; k0 < K; k0 += 64){
#pragma unroll
    for (int i = 0; i < 8; ++i){
      const int c = wave*8 + i;        // 0..31; <16 = A chunks, else B chunks
      if (c < 16){
        const ushort* g = A + (size_t)(m0 + c*8 + srow) * K + k0 + scol;
        __builtin_amdgcn_global_load_lds((const AS1 void*)g, (AS3 void*)(As + c*512), 16, 0, 0);
      } else {
        const ushort* g = Bt + (size_t)(n0 + (c-16)*8 + srow) * K + k0 + scol;
        __builtin_amdgcn_global_load_lds((const AS1 void*)g, (AS3 void*)(Bs + (c-16)*512), 16, 0, 0);
      }
    }
    __syncthreads();
#pragma unroll
    for (int kk = 0; kk < 2; ++kk){
      bfrag af[4], bf[4];
#pragma unroll
      for (int mi = 0; mi < 4; ++mi)
        af[mi] = *(const bfrag*)(As + (wm*64 + mi*16 + lcol)*64 + kk*32 + lrow*8);
#pragma unroll
      for (int ni = 0; ni < 4; ++ni)
        bf[ni] = *(const bfrag*)(Bs + (wn*64 + ni*16 + lcol)*64 + kk*32 + lrow*8);
#pragma unroll
      for (int mi = 0; mi < 4; ++mi)
#pragma unroll
        for (int ni = 0; ni < 4; ++ni)
          acc[mi][ni] = __builtin_amdgcn_mfma_f32_16x16x32_bf16(af[mi], bf[ni], acc[mi][ni], 0, 0, 0);
    }
    __syncthreads();
  }
#pragma unroll
  for (int mi = 0; mi < 4; ++mi){
#pragma unroll
    for (int ni = 0; ni < 4; ++ni){
      const int col = n0 + wn*64 + ni*16 + lcol;
      const float bsv = HAS_BIAS ? bias[col] : 0.f;
#pragma unroll
      for (int r = 0; r < 4; ++r){
        const size_t row = (size_t)m0 + wm*64 + mi*16 + lrow*4 + r;
        const float v = acc[mi][ni][r] + bsv;
        if (OUT_BF16) ((ushort*)Cout)[row * N + col] = f2bf(v);
        else          ((float*) Cout)[row * N + col] = v;
      }
    }
  }
}

// ---- in-place RoPE on q (cols 0..2047) and k (cols 2048..2303) of qkv ----
__global__ void k_rope(ushort* __restrict__ qkv, const float* __restrict__ cosb,
                       const float* __restrict__ sinb){
  const int s = blockIdx.x, b = blockIdx.y;
  ushort* rp = qkv + ((size_t)(b*Ssz + s)) * NQKV;
  const float* cb = cosb + s*64;
  const float* sb = sinb + s*64;
  for (int i = threadIdx.x; i < 18*64; i += 256){  // 16 q-heads + 2 kv-heads
    const int hh = i >> 6, d = i & 63;
    ushort* p = rp + hh*128 + d;
    const float x1 = bf2f(p[0]), x2 = bf2f(p[64]);
    const float c = cb[d], sn = sb[d];
    p[0]  = f2bf(x1*c  - x2*sn);
    p[64] = f2bf(x1*sn + x2*c);
  }
}

// ---- V relayout: qkv cols [2304,2560) (b,s,kv,d) -> vt (b,kv,d,s) ----
__global__ void k_vt(const ushort* __restrict__ qkv, ushort* __restrict__ vt){
  __shared__ ushort t[64][65];
  const int s0 = blockIdx.x * 64, d0 = blockIdx.y * 64;
  const int bkv = blockIdx.z, b = bkv >> 1, kv = bkv & 1;
  for (int i = threadIdx.x; i < 4096; i += 256){
    const int sl = i >> 6, dl = i & 63;
    t[sl][dl] = qkv[(size_t)(b*Ssz + s0 + sl)*NQKV + 2304 + kv*128 + d0 + dl];
  }
  __syncthreads();
  for (int i = threadIdx.x; i < 4096; i += 256){
    const int dl = i >> 6, sl = i & 63;
    vt[((size_t)(bkv*128 + d0 + dl))*Ssz + s0 + sl] = t[sl][dl];
  }
}

// ---- causal GQA flash attention, 8-wave blocks, SWAPPED QK^T softmax ----
// Waves 0-3 -> q-tile B=31-p, waves 4-7 -> q-tile A=p, concurrently.
// step: S^T = mfma(K,Q) -> lane owns q=lcol -> in-lane softmax (log2 domain,
// 2 shfls), defer-max rescale skip (T13), P[q][k] packed ds_write_b64 -> PV.
// K double-buffered via global_load_lds (XOR-swizzled source, rule #21);
// V reg-split staged (T14). launch_bounds(512,4) caps VGPR at 128.
__global__ __launch_bounds__(512, 4) void k_attn(const ushort* __restrict__ qkv,
                                                 const ushort* __restrict__ vt,
                                                 ushort* __restrict__ out){
  __shared__ __attribute__((aligned(16))) char klds2[2*16384];  // K dbuf, 64 rows x 256B, swizzled
  __shared__ __attribute__((aligned(16))) char vlds[128*144];   // V^T 128 x (64 bf16 + 16B pad)
  __shared__ __attribute__((aligned(16))) char plds[8*2304];    // per-wave P 16 x (64 bf16 + pad)
  const int p = blockIdx.x, h = blockIdx.y, b = blockIdx.z;
  const int qtA = p, qtB = 31 - p;                // qtB >= 16 > qtA <= 15 always
  const int kvh = h >> 3;                         // rep = NH/NKV = 8
  const int tid = threadIdx.x, wave = tid >> 6, lane = tid & 63;
  const int grp = wave >> 2, w4 = wave & 3;       // grp 0 -> tile B, grp 1 -> tile A
  const int qx = grp ? qtA : qtB;
  const int lrow = lane >> 4, lcol = lane & 15;

  bfrag qf[4];
  {
    const ushort* qp = qkv + ((size_t)b*Ssz + qx*64 + w4*16 + lcol)*NQKV + h*HDd + lrow*8;
#pragma unroll
    for (int kk = 0; kk < 4; ++kk) qf[kk] = *(const bfrag*)(qp + kk*32);
  }
  facc acc[8] = {};
  float m = -1e30f, l = 0.f;               // per-lane softmax state for q = lcol (log2 domain)

  const ushort* kb = qkv + (size_t)b*Ssz*NQKV + Hsz + kvh*HDd;
  const ushort* vb = vt + ((size_t)(b*NKVh + kvh))*HDd*Ssz;
  char* pw = plds + wave*2304;
  const int qloc = w4*16 + lcol;           // this lane's q row within the 64-row q-tile

  // K tile t -> dst via global_load_lds DMA; LDS slot (row,cb) holds
  // K[row][cb ^ ((row&7)<<4)] (pre-swizzled source, linear dest).
  auto issueK = [&](int t, char* dst){
    const ushort* kt = kb + (size_t)t*64*NQKV;
#pragma unroll
    for (int i = 0; i < 2; ++i){
      const int row = i*32 + wave*4 + (lane >> 4);
      const int cb  = (lane & 15) * 16;
      const char* g = (const char*)(kt + (size_t)row*NQKV) + (cb ^ ((row & 7) << 4));
      __builtin_amdgcn_global_load_lds((const AS1 void*)g,
          (AS3 void*)(dst + i*8192 + wave*1024), 16, 0, 0);
    }
  };

  int4 vreg[2];                          // V staging registers (T14 split)
  auto loadV = [&](int t){
#pragma unroll
    for (int i = 0; i < 2; ++i){
      const int c = i*512 + tid;
      vreg[i] = *(const int4*)((const char*)(vb + (size_t)(c>>3)*Ssz + t*64) + (c&7)*16);
    }
  };
  auto writeV = [&](){
#pragma unroll
    for (int i = 0; i < 2; ++i){
      const int c = i*512 + tid;
      *(int4*)(vlds + (c>>3)*144 + (c&7)*16) = vreg[i];
    }
  };

  // one tile-step: swapped QK^T -> in-lane softmax -> P pack -> PV
  auto step = [&](int t, const char* kcur){
    facc sc[4] = {};
#pragma unroll
    for (int kk = 0; kk < 4; ++kk){        // S^T = K·Q^T: 16 MFMA, swizzled K reads
#pragma unroll
      for (int nt = 0; nt < 4; ++nt){
        const bfrag kf = *(const bfrag*)(kcur + (nt*16 + lcol)*256 +
                                         ((kk*64 + lrow*16) ^ ((lcol & 7) << 4)));
        sc[nt] = __builtin_amdgcn_mfma_f32_16x16x32_bf16(kf, qf[kk], sc[nt], 0, 0, 0);
      }
    }
    const bool diag = (t == qx);
    float e[4][4];
    float tm = -1e30f;
#pragma unroll
    for (int nt = 0; nt < 4; ++nt){
#pragma unroll
      for (int r = 0; r < 4; ++r){
        float sv = sc[nt][r] * 0.12752585778442352f;   // log2(e)/sqrt(128)
        if (diag && (nt*16 + lrow*4 + r) > qloc) sv = -1e30f;
        e[nt][r] = sv;
        tm = fmaxf(tm, sv);
      }
    }
    tm = fmaxf(tm, __shfl_xor(tm, 16));    // reduce over the 4 k-groups
    tm = fmaxf(tm, __shfl_xor(tm, 32));
    float mn = m, corr = 1.f;
    if (!__all(tm <= m + 11.5f)){          // defer-max: skip rescale when bounded
      mn = fmaxf(m, tm);
      corr = exp2f(m - mn);
#pragma unroll
      for (int r = 0; r < 4; ++r){
        const float ct = __shfl(corr, lrow*4 + r);
#pragma unroll
        for (int dt = 0; dt < 8; ++dt) acc[dt][r] *= ct;
      }
      m = mn;
    }
    float rs = 0.f;
#pragma unroll
    for (int nt = 0; nt < 4; ++nt)
#pragma unroll
      for (int r = 0; r < 4; ++r){
        const float ev = exp2f(e[nt][r] - mn);
        e[nt][r] = ev; rs += ev;
      }
    rs += __shfl_xor(rs, 16);
    rs += __shfl_xor(rs, 32);
    l = l*corr + rs;
#pragma unroll
    for (int nt = 0; nt < 4; ++nt){        // P[q][k] -> LDS: 4 x ds_write_b64
      ushort4 w;
      w.x = f2bf(e[nt][0]); w.y = f2bf(e[nt][1]);
      w.z = f2bf(e[nt][2]); w.w = f2bf(e[nt][3]);
      *(ushort4*)(pw + lcol*144 + nt*32 + lrow*8) = w;
    }
    asm volatile("s_waitcnt lgkmcnt(0)" ::: "memory");
#pragma unroll
    for (int kk2 = 0; kk2 < 2; ++kk2){     // PV: 16 MFMA
      const bfrag pa = *(const bfrag*)(pw + lcol*144 + kk2*64 + lrow*16);
#pragma unroll
      for (int dt = 0; dt < 8; ++dt){
        const bfrag vf = *(const bfrag*)(vlds + (dt*16 + lcol)*144 + kk2*64 + lrow*16);
        acc[dt] = __builtin_amdgcn_mfma_f32_16x16x32_bf16(pa, vf, acc[dt], 0, 0, 0);
      }
    }
  };

  // prologue: tile 0
  issueK(0, klds2);
  loadV(0);
  writeV();
  __syncthreads();                         // drains K DMA (vmcnt) + V writes (lgkm)

  int cur = 0;
  for (int t = 0; t <= qtB; ++t){
    const bool more = (t < qtB);
    if (more){
      issueK(t + 1, klds2 + (cur ^ 1)*16384);  // DMA next K tile into other buffer
      loadV(t + 1);                            // V loads in flight under compute
    }
    if (t <= qx) step(t, klds2 + cur*16384);
    __syncthreads();                       // all reads done; K DMA + V loads drained
    if (more) writeV();
    __syncthreads();                       // vlds(t+1) visible to all waves
    cur ^= 1;
  }

  float lt[4];
#pragma unroll
  for (int r = 0; r < 4; ++r) lt[r] = __shfl(l, lrow*4 + r);
#pragma unroll
  for (int r = 0; r < 4; ++r){
    const float inv = 1.f / lt[r];
    ushort* op = out + ((size_t)b*Ssz + qx*64 + w4*16 + lrow*4 + r)*Hsz + h*HDd;
#pragma unroll
    for (int dt = 0; dt < 8; ++dt)
      op[dt*16 + lcol] = f2bf(acc[dt][r] * inv);
  }
}

extern "C" void kernel_launch(void* const* d_in, const int* in_sizes, int n_in,
                              void* d_out, int out_size, void* d_ws, size_t ws_size,
                              hipStream_t stream){
  (void)in_sizes; (void)n_in; (void)out_size;
  const float* hs  = (const float*)d_in[0];
  // d_in[1] = attention_mask: exactly causal 0/-1e9, applied analytically in k_attn
  const int*   pos = (const int*)  d_in[2];
  const float* Wq  = (const float*)d_in[3];
  const float* bq  = (const float*)d_in[4];
  const float* Wk  = (const float*)d_in[5];
  const float* bk  = (const float*)d_in[6];
  const float* Wv  = (const float*)d_in[7];
  const float* bv  = (const float*)d_in[8];
  const float* Wo  = (const float*)d_in[9];

  if (ws_size < 59779072) return;  // need ~57 MB scratch

  char* ws = (char*)d_ws;
  ushort* Xbf   = (ushort*)(ws + 0);          // 16,777,216 B; reused as attn output
  ushort* WqkvT = (ushort*)(ws + 16777216);   // 10,485,760 B (2560 x 2048 bf16)
  ushort* WoT   = (ushort*)(ws + 27262976);   //  8,388,608 B
  float*  bqkv  = (float*) (ws + 35651584);   //     10,240 B
  float*  cosb  = (float*) (ws + 35661824);   //    524,288 B
  float*  sinb  = (float*) (ws + 36186112);   //    524,288 B
  ushort* qkv   = (ushort*)(ws + 36710400);   // 20,971,520 B (4096 x 2560 bf16)
  ushort* vt    = (ushort*)(ws + 57681920);   //  2,097,152 B
  ushort* attn  = Xbf;

  k_convert  <<<8192, 256, 0, stream>>>(hs, Xbf);
  k_transpose<<<dim3(64,64), dim3(32,8), 0, stream>>>(Wq, WqkvT, 2048, 0);
  k_transpose<<<dim3(64, 8), dim3(32,8), 0, stream>>>(Wk, WqkvT, 256, 2048);
  k_transpose<<<dim3(64, 8), dim3(32,8), 0, stream>>>(Wv, WqkvT, 256, 2304);
  k_transpose<<<dim3(64,64), dim3(32,8), 0, stream>>>(Wo, WoT, 2048, 0);
  k_bias     <<<10, 256, 0, stream>>>(bq, bk, bv, bqkv);
  k_ropetab  <<<2048, 64, 0, stream>>>(pos, cosb, sinb);
  k_gemm<true,  true ><<<dim3(32,20), 256, 0, stream>>>(Xbf, WqkvT, bqkv, qkv, 2560, 2048);
  k_rope     <<<dim3(2048,2), 256, 0, stream>>>(qkv, cosb, sinb);
  k_vt       <<<dim3(32,2,4), 256, 0, stream>>>(qkv, vt);
  k_attn     <<<dim3(16,16,2), 512, 0, stream>>>(qkv, vt, attn);
  k_gemm<false, false><<<dim3(32,16), 256, 0, stream>>>(attn, WoT, nullptr, d_out, 2048, 2048);
}

// Round 7
// 246.555 us; speedup vs baseline: 1.7112x; 1.2059x over previous
//
#include <hip/hip_runtime.h>
#include <stdint.h>

// Problem constants (B,S,H)=(2,2048,2048), NH=16, NKV=2, HD=128, theta=1e6
#define Bsz  2
#define Ssz  2048
#define Hsz  2048
#define NHh  16
#define NKVh 2
#define HDd  128
#define NQKV 2560   // H + 2*KV = 2048 + 512

typedef __attribute__((ext_vector_type(8))) short bfrag;  // 8 x bf16 (4 VGPRs)
typedef __attribute__((ext_vector_type(4))) float facc;   // MFMA f32 accum

#define AS1 __attribute__((address_space(1)))
#define AS3 __attribute__((address_space(3)))

__device__ __forceinline__ ushort f2bf(float x){
  union { float f; uint32_t u; } v; v.f = x;
  return (ushort)((v.u + 0x7fffu + ((v.u >> 16) & 1u)) >> 16);
}
__device__ __forceinline__ float bf2f(ushort x){
  union { uint32_t u; float f; } v; v.u = ((uint32_t)x) << 16; return v.f;
}

// ---- fp32 -> bf16 bulk convert (X) ----
__global__ void k_convert(const float* __restrict__ in, ushort* __restrict__ out){
  const size_t i = ((size_t)blockIdx.x * 256 + threadIdx.x) * 4;
  const float4 v = *(const float4*)(in + i);
  ushort4 o;
  o.x = f2bf(v.x); o.y = f2bf(v.y); o.z = f2bf(v.z); o.w = f2bf(v.w);
  *(ushort4*)(out + i) = o;
}

// ---- transpose-convert: in (2048 x N) f32 row-major -> out bf16 rows (rowoff+n), ld 2048 ----
__global__ void k_transpose(const float* __restrict__ in, ushort* __restrict__ out,
                            int N, int rowoff){
  __shared__ float t[32][33];
  const int k0 = blockIdx.x * 32, n0 = blockIdx.y * 32;
  const int tx = threadIdx.x, ty = threadIdx.y; // 32 x 8
#pragma unroll
  for (int i = 0; i < 4; ++i)
    t[ty + i*8][tx] = in[(size_t)(k0 + ty + i*8) * N + n0 + tx];
  __syncthreads();
#pragma unroll
  for (int i = 0; i < 4; ++i)
    out[(size_t)(rowoff + n0 + ty + i*8) * 2048 + k0 + tx] = f2bf(t[tx][ty + i*8]);
}

// ---- concat biases (fp32) ----
__global__ void k_bias(const float* __restrict__ bq, const float* __restrict__ bk,
                       const float* __restrict__ bv, float* __restrict__ o){
  const int i = blockIdx.x * 256 + threadIdx.x;
  if (i < 2048)      o[i] = bq[i];
  else if (i < 2304) o[i] = bk[i - 2048];
  else if (i < 2560) o[i] = bv[i - 2304];
}

// ---- RoPE cos/sin table from position_ids ----
__global__ void k_ropetab(const int* __restrict__ pos, float* __restrict__ cosb,
                          float* __restrict__ sinb){
  const int s = blockIdx.x, j = threadIdx.x; // 64 threads
  const float p = (float)pos[s];
  const float fr = expf(-(float)j * (13.815510557964274f / 64.f)); // 1/theta^(j/64)
  const float t = p * fr;
  cosb[s*64 + j] = cosf(t);
  sinb[s*64 + j] = sinf(t);
}

// ---- 2-phase prefetch bf16 GEMM (T3-minimum): C[M,N] = A[M,K] * Bt[N,K]^T (+bias) ----
// BK=32, LDS double-buffered (32KB total). STAGE(t+1) issued BEFORE ds_read+MFMA of
// tile t; single barrier per K-step drains vmcnt with a full compute phase of slack.
template<bool HAS_BIAS, bool OUT_BF16>
__global__ __launch_bounds__(256, 3) void k_gemm(const ushort* __restrict__ A,
                                                 const ushort* __restrict__ Bt,
                                                 const float* __restrict__ bias,
                                                 void* __restrict__ Cout, int N, int K){
  __shared__ ushort As[2][128*32];
  __shared__ ushort Bs[2][128*32];
  const int m0 = blockIdx.x * 128;
  const int n0 = blockIdx.y * 128;
  const int tid = threadIdx.x;
  const int wave = tid >> 6, lane = tid & 63;
  const int wm = wave >> 1, wn = wave & 1;
  const int lrow = lane >> 4, lcol = lane & 15;
  facc acc[4][4] = {};

  // stage K-tile t into buffer buf: 8 chunks x 64 slots x 16B per matrix.
  // LDS dst is wave-uniform base (+ lane*16 by HW); global src per-lane.
  auto stage = [&](int t, int buf){
    const int k0 = t * 32;
#pragma unroll
    for (int i = 0; i < 2; ++i){
      const int chunk = wave*2 + i;            // 0..7
      const int slot  = chunk*64 + lane;       // 0..511
      const int row   = slot >> 2, col8 = (slot & 3) * 8;
      const ushort* ga = A  + (size_t)(m0 + row) * K + k0 + col8;
      const ushort* gb = Bt + (size_t)(n0 + row) * K + k0 + col8;
      __builtin_amdgcn_global_load_lds((const AS1 void*)ga,
          (AS3 void*)(&As[buf][chunk*512]), 16, 0, 0);
      __builtin_amdgcn_global_load_lds((const AS1 void*)gb,
          (AS3 void*)(&Bs[buf][chunk*512]), 16, 0, 0);
    }
  };

  stage(0, 0);
  __syncthreads();
  const int nT = K >> 5;
  for (int t = 0; t < nT; ++t){
    const int buf = t & 1;
    if (t + 1 < nT) stage(t + 1, buf ^ 1);   // prefetch next tile (other buffer)
    bfrag af[4], bf[4];
#pragma unroll
    for (int mi = 0; mi < 4; ++mi)
      af[mi] = *(const bfrag*)(&As[buf][(wm*64 + mi*16 + lcol)*32 + lrow*8]);
#pragma unroll
    for (int ni = 0; ni < 4; ++ni)
      bf[ni] = *(const bfrag*)(&Bs[buf][(wn*64 + ni*16 + lcol)*32 + lrow*8]);
#pragma unroll
    for (int mi = 0; mi < 4; ++mi)
#pragma unroll
      for (int ni = 0; ni < 4; ++ni)
        acc[mi][ni] = __builtin_amdgcn_mfma_f32_16x16x32_bf16(af[mi], bf[ni], acc[mi][ni], 0, 0, 0);
    __syncthreads();                         // drains prefetch loads + LDS reads
  }
#pragma unroll
  for (int mi = 0; mi < 4; ++mi){
#pragma unroll
    for (int ni = 0; ni < 4; ++ni){
      const int col = n0 + wn*64 + ni*16 + lcol;
      const float bsv = HAS_BIAS ? bias[col] : 0.f;
#pragma unroll
      for (int r = 0; r < 4; ++r){
        const size_t row = (size_t)m0 + wm*64 + mi*16 + lrow*4 + r;
        const float v = acc[mi][ni][r] + bsv;
        if (OUT_BF16) ((ushort*)Cout)[row * N + col] = f2bf(v);
        else          ((float*) Cout)[row * N + col] = v;
      }
    }
  }
}

// ---- in-place RoPE on q (cols 0..2047) and k (cols 2048..2303) of qkv ----
__global__ void k_rope(ushort* __restrict__ qkv, const float* __restrict__ cosb,
                       const float* __restrict__ sinb){
  const int s = blockIdx.x, b = blockIdx.y;
  ushort* rp = qkv + ((size_t)(b*Ssz + s)) * NQKV;
  const float* cb = cosb + s*64;
  const float* sb = sinb + s*64;
  for (int i = threadIdx.x; i < 18*64; i += 256){  // 16 q-heads + 2 kv-heads
    const int hh = i >> 6, d = i & 63;
    ushort* p = rp + hh*128 + d;
    const float x1 = bf2f(p[0]), x2 = bf2f(p[64]);
    const float c = cb[d], sn = sb[d];
    p[0]  = f2bf(x1*c  - x2*sn);
    p[64] = f2bf(x1*sn + x2*c);
  }
}

// ---- V relayout: qkv cols [2304,2560) (b,s,kv,d) -> vt (b,kv,d,s) ----
__global__ void k_vt(const ushort* __restrict__ qkv, ushort* __restrict__ vt){
  __shared__ ushort t[64][65];
  const int s0 = blockIdx.x * 64, d0 = blockIdx.y * 64;
  const int bkv = blockIdx.z, b = bkv >> 1, kv = bkv & 1;
  for (int i = threadIdx.x; i < 4096; i += 256){
    const int sl = i >> 6, dl = i & 63;
    t[sl][dl] = qkv[(size_t)(b*Ssz + s0 + sl)*NQKV + 2304 + kv*128 + d0 + dl];
  }
  __syncthreads();
  for (int i = threadIdx.x; i < 4096; i += 256){
    const int dl = i >> 6, sl = i & 63;
    vt[((size_t)(bkv*128 + d0 + dl))*Ssz + s0 + sl] = t[sl][dl];
  }
}

// ---- causal GQA flash attention, 8-wave blocks, SWAPPED QK^T softmax ----
// (unchanged from round 6: 110 us, verified)
__global__ __launch_bounds__(512, 4) void k_attn(const ushort* __restrict__ qkv,
                                                 const ushort* __restrict__ vt,
                                                 ushort* __restrict__ out){
  __shared__ __attribute__((aligned(16))) char klds2[2*16384];  // K dbuf, 64 rows x 256B, swizzled
  __shared__ __attribute__((aligned(16))) char vlds[128*144];   // V^T 128 x (64 bf16 + 16B pad)
  __shared__ __attribute__((aligned(16))) char plds[8*2304];    // per-wave P 16 x (64 bf16 + pad)
  const int p = blockIdx.x, h = blockIdx.y, b = blockIdx.z;
  const int qtA = p, qtB = 31 - p;                // qtB >= 16 > qtA <= 15 always
  const int kvh = h >> 3;                         // rep = NH/NKV = 8
  const int tid = threadIdx.x, wave = tid >> 6, lane = tid & 63;
  const int grp = wave >> 2, w4 = wave & 3;       // grp 0 -> tile B, grp 1 -> tile A
  const int qx = grp ? qtA : qtB;
  const int lrow = lane >> 4, lcol = lane & 15;

  bfrag qf[4];
  {
    const ushort* qp = qkv + ((size_t)b*Ssz + qx*64 + w4*16 + lcol)*NQKV + h*HDd + lrow*8;
#pragma unroll
    for (int kk = 0; kk < 4; ++kk) qf[kk] = *(const bfrag*)(qp + kk*32);
  }
  facc acc[8] = {};
  float m = -1e30f, l = 0.f;               // per-lane softmax state for q = lcol (log2 domain)

  const ushort* kb = qkv + (size_t)b*Ssz*NQKV + Hsz + kvh*HDd;
  const ushort* vb = vt + ((size_t)(b*NKVh + kvh))*HDd*Ssz;
  char* pw = plds + wave*2304;
  const int qloc = w4*16 + lcol;           // this lane's q row within the 64-row q-tile

  auto issueK = [&](int t, char* dst){
    const ushort* kt = kb + (size_t)t*64*NQKV;
#pragma unroll
    for (int i = 0; i < 2; ++i){
      const int row = i*32 + wave*4 + (lane >> 4);
      const int cb  = (lane & 15) * 16;
      const char* g = (const char*)(kt + (size_t)row*NQKV) + (cb ^ ((row & 7) << 4));
      __builtin_amdgcn_global_load_lds((const AS1 void*)g,
          (AS3 void*)(dst + i*8192 + wave*1024), 16, 0, 0);
    }
  };

  int4 vreg[2];                          // V staging registers (T14 split)
  auto loadV = [&](int t){
#pragma unroll
    for (int i = 0; i < 2; ++i){
      const int c = i*512 + tid;
      vreg[i] = *(const int4*)((const char*)(vb + (size_t)(c>>3)*Ssz + t*64) + (c&7)*16);
    }
  };
  auto writeV = [&](){
#pragma unroll
    for (int i = 0; i < 2; ++i){
      const int c = i*512 + tid;
      *(int4*)(vlds + (c>>3)*144 + (c&7)*16) = vreg[i];
    }
  };

  auto step = [&](int t, const char* kcur){
    facc sc[4] = {};
#pragma unroll
    for (int kk = 0; kk < 4; ++kk){        // S^T = K·Q^T: 16 MFMA, swizzled K reads
#pragma unroll
      for (int nt = 0; nt < 4; ++nt){
        const bfrag kf = *(const bfrag*)(kcur + (nt*16 + lcol)*256 +
                                         ((kk*64 + lrow*16) ^ ((lcol & 7) << 4)));
        sc[nt] = __builtin_amdgcn_mfma_f32_16x16x32_bf16(kf, qf[kk], sc[nt], 0, 0, 0);
      }
    }
    const bool diag = (t == qx);
    float e[4][4];
    float tm = -1e30f;
#pragma unroll
    for (int nt = 0; nt < 4; ++nt){
#pragma unroll
      for (int r = 0; r < 4; ++r){
        float sv = sc[nt][r] * 0.12752585778442352f;   // log2(e)/sqrt(128)
        if (diag && (nt*16 + lrow*4 + r) > qloc) sv = -1e30f;
        e[nt][r] = sv;
        tm = fmaxf(tm, sv);
      }
    }
    tm = fmaxf(tm, __shfl_xor(tm, 16));    // reduce over the 4 k-groups
    tm = fmaxf(tm, __shfl_xor(tm, 32));
    float mn = m, corr = 1.f;
    if (!__all(tm <= m + 11.5f)){          // defer-max: skip rescale when bounded
      mn = fmaxf(m, tm);
      corr = exp2f(m - mn);
#pragma unroll
      for (int r = 0; r < 4; ++r){
        const float ct = __shfl(corr, lrow*4 + r);
#pragma unroll
        for (int dt = 0; dt < 8; ++dt) acc[dt][r] *= ct;
      }
      m = mn;
    }
    float rs = 0.f;
#pragma unroll
    for (int nt = 0; nt < 4; ++nt)
#pragma unroll
      for (int r = 0; r < 4; ++r){
        const float ev = exp2f(e[nt][r] - mn);
        e[nt][r] = ev; rs += ev;
      }
    rs += __shfl_xor(rs, 16);
    rs += __shfl_xor(rs, 32);
    l = l*corr + rs;
#pragma unroll
    for (int nt = 0; nt < 4; ++nt){        // P[q][k] -> LDS: 4 x ds_write_b64
      ushort4 w;
      w.x = f2bf(e[nt][0]); w.y = f2bf(e[nt][1]);
      w.z = f2bf(e[nt][2]); w.w = f2bf(e[nt][3]);
      *(ushort4*)(pw + lcol*144 + nt*32 + lrow*8) = w;
    }
    asm volatile("s_waitcnt lgkmcnt(0)" ::: "memory");
#pragma unroll
    for (int kk2 = 0; kk2 < 2; ++kk2){     // PV: 16 MFMA
      const bfrag pa = *(const bfrag*)(pw + lcol*144 + kk2*64 + lrow*16);
#pragma unroll
      for (int dt = 0; dt < 8; ++dt){
        const bfrag vf = *(const bfrag*)(vlds + (dt*16 + lcol)*144 + kk2*64 + lrow*16);
        acc[dt] = __builtin_amdgcn_mfma_f32_16x16x32_bf16(pa, vf, acc[dt], 0, 0, 0);
      }
    }
  };

  // prologue: tile 0
  issueK(0, klds2);
  loadV(0);
  writeV();
  __syncthreads();                         // drains K DMA (vmcnt) + V writes (lgkm)

  int cur = 0;
  for (int t = 0; t <= qtB; ++t){
    const bool more = (t < qtB);
    if (more){
      issueK(t + 1, klds2 + (cur ^ 1)*16384);  // DMA next K tile into other buffer
      loadV(t + 1);                            // V loads in flight under compute
    }
    if (t <= qx) step(t, klds2 + cur*16384);
    __syncthreads();                       // all reads done; K DMA + V loads drained
    if (more) writeV();
    __syncthreads();                       // vlds(t+1) visible to all waves
    cur ^= 1;
  }

  float lt[4];
#pragma unroll
  for (int r = 0; r < 4; ++r) lt[r] = __shfl(l, lrow*4 + r);
#pragma unroll
  for (int r = 0; r < 4; ++r){
    const float inv = 1.f / lt[r];
    ushort* op = out + ((size_t)b*Ssz + qx*64 + w4*16 + lrow*4 + r)*Hsz + h*HDd;
#pragma unroll
    for (int dt = 0; dt < 8; ++dt)
      op[dt*16 + lcol] = f2bf(acc[dt][r] * inv);
  }
}

extern "C" void kernel_launch(void* const* d_in, const int* in_sizes, int n_in,
                              void* d_out, int out_size, void* d_ws, size_t ws_size,
                              hipStream_t stream){
  (void)in_sizes; (void)n_in; (void)out_size;
  const float* hs  = (const float*)d_in[0];
  // d_in[1] = attention_mask: exactly causal 0/-1e9, applied analytically in k_attn
  const int*   pos = (const int*)  d_in[2];
  const float* Wq  = (const float*)d_in[3];
  const float* bq  = (const float*)d_in[4];
  const float* Wk  = (const float*)d_in[5];
  const float* bk  = (const float*)d_in[6];
  const float* Wv  = (const float*)d_in[7];
  const float* bv  = (const float*)d_in[8];
  const float* Wo  = (const float*)d_in[9];

  if (ws_size < 59779072) return;  // need ~57 MB scratch

  char* ws = (char*)d_ws;
  ushort* Xbf   = (ushort*)(ws + 0);          // 16,777,216 B; reused as attn output
  ushort* WqkvT = (ushort*)(ws + 16777216);   // 10,485,760 B (2560 x 2048 bf16)
  ushort* WoT   = (ushort*)(ws + 27262976);   //  8,388,608 B
  float*  bqkv  = (float*) (ws + 35651584);   //     10,240 B
  float*  cosb  = (float*) (ws + 35661824);   //    524,288 B
  float*  sinb  = (float*) (ws + 36186112);   //    524,288 B
  ushort* qkv   = (ushort*)(ws + 36710400);   // 20,971,520 B (4096 x 2560 bf16)
  ushort* vt    = (ushort*)(ws + 57681920);   //  2,097,152 B
  ushort* attn  = Xbf;

  k_convert  <<<8192, 256, 0, stream>>>(hs, Xbf);
  k_transpose<<<dim3(64,64), dim3(32,8), 0, stream>>>(Wq, WqkvT, 2048, 0);
  k_transpose<<<dim3(64, 8), dim3(32,8), 0, stream>>>(Wk, WqkvT, 256, 2048);
  k_transpose<<<dim3(64, 8), dim3(32,8), 0, stream>>>(Wv, WqkvT, 256, 2304);
  k_transpose<<<dim3(64,64), dim3(32,8), 0, stream>>>(Wo, WoT, 2048, 0);
  k_bias     <<<10, 256, 0, stream>>>(bq, bk, bv, bqkv);
  k_ropetab  <<<2048, 64, 0, stream>>>(pos, cosb, sinb);
  k_gemm<true,  true ><<<dim3(32,20), 256, 0, stream>>>(Xbf, WqkvT, bqkv, qkv, 2560, 2048);
  k_rope     <<<dim3(2048,2), 256, 0, stream>>>(qkv, cosb, sinb);
  k_vt       <<<dim3(32,2,4), 256, 0, stream>>>(qkv, vt);
  k_attn     <<<dim3(16,16,2), 512, 0, stream>>>(qkv, vt, attn);
  k_gemm<false, false><<<dim3(32,16), 256, 0, stream>>>(attn, WoT, nullptr, d_out, 2048, 2048);
}

// Round 8
// 243.992 us; speedup vs baseline: 1.7291x; 1.0105x over previous
//
#include <hip/hip_runtime.h>
#include <stdint.h>

// Problem constants (B,S,H)=(2,2048,2048), NH=16, NKV=2, HD=128, theta=1e6
#define Bsz  2
#define Ssz  2048
#define Hsz  2048
#define NHh  16
#define NKVh 2
#define HDd  128
#define NQKV 2560   // H + 2*KV = 2048 + 512

typedef __attribute__((ext_vector_type(8))) short bfrag;  // 8 x bf16 (4 VGPRs)
typedef __attribute__((ext_vector_type(4))) float facc;   // MFMA f32 accum

#define AS1 __attribute__((address_space(1)))
#define AS3 __attribute__((address_space(3)))

__device__ __forceinline__ ushort f2bf(float x){
  union { float f; uint32_t u; } v; v.f = x;
  return (ushort)((v.u + 0x7fffu + ((v.u >> 16) & 1u)) >> 16);
}
__device__ __forceinline__ float bf2f(ushort x){
  union { uint32_t u; float f; } v; v.u = ((uint32_t)x) << 16; return v.f;
}

// ---- fp32 -> bf16 bulk convert (X) ----
__global__ void k_convert(const float* __restrict__ in, ushort* __restrict__ out){
  const size_t i = ((size_t)blockIdx.x * 256 + threadIdx.x) * 4;
  const float4 v = *(const float4*)(in + i);
  ushort4 o;
  o.x = f2bf(v.x); o.y = f2bf(v.y); o.z = f2bf(v.z); o.w = f2bf(v.w);
  *(ushort4*)(out + i) = o;
}

// ---- transpose-convert: in (2048 x N) f32 row-major -> out bf16 rows (rowoff+n), ld 2048 ----
__global__ void k_transpose(const float* __restrict__ in, ushort* __restrict__ out,
                            int N, int rowoff){
  __shared__ float t[32][33];
  const int k0 = blockIdx.x * 32, n0 = blockIdx.y * 32;
  const int tx = threadIdx.x, ty = threadIdx.y; // 32 x 8
#pragma unroll
  for (int i = 0; i < 4; ++i)
    t[ty + i*8][tx] = in[(size_t)(k0 + ty + i*8) * N + n0 + tx];
  __syncthreads();
#pragma unroll
  for (int i = 0; i < 4; ++i)
    out[(size_t)(rowoff + n0 + ty + i*8) * 2048 + k0 + tx] = f2bf(t[tx][ty + i*8]);
}

// ---- concat biases (fp32) ----
__global__ void k_bias(const float* __restrict__ bq, const float* __restrict__ bk,
                       const float* __restrict__ bv, float* __restrict__ o){
  const int i = blockIdx.x * 256 + threadIdx.x;
  if (i < 2048)      o[i] = bq[i];
  else if (i < 2304) o[i] = bk[i - 2048];
  else if (i < 2560) o[i] = bv[i - 2304];
}

// ---- RoPE cos/sin table from position_ids ----
__global__ void k_ropetab(const int* __restrict__ pos, float* __restrict__ cosb,
                          float* __restrict__ sinb){
  const int s = blockIdx.x, j = threadIdx.x; // 64 threads
  const float p = (float)pos[s];
  const float fr = expf(-(float)j * (13.815510557964274f / 64.f)); // 1/theta^(j/64)
  const float t = p * fr;
  cosb[s*64 + j] = cosf(t);
  sinb[s*64 + j] = sinf(t);
}

// ---- 2-phase prefetch bf16 GEMM (T3-minimum): C[M,N] = A[M,K] * Bt[N,K]^T (+bias) ----
// BK=32, LDS double-buffered (32KB total). STAGE(t+1) issued BEFORE ds_read+MFMA of
// tile t; single barrier per K-step drains vmcnt with a full compute phase of slack.
template<bool HAS_BIAS, bool OUT_BF16>
__global__ __launch_bounds__(256, 3) void k_gemm(const ushort* __restrict__ A,
                                                 const ushort* __restrict__ Bt,
                                                 const float* __restrict__ bias,
                                                 void* __restrict__ Cout, int N, int K){
  __shared__ ushort As[2][128*32];
  __shared__ ushort Bs[2][128*32];
  const int m0 = blockIdx.x * 128;
  const int n0 = blockIdx.y * 128;
  const int tid = threadIdx.x;
  const int wave = tid >> 6, lane = tid & 63;
  const int wm = wave >> 1, wn = wave & 1;
  const int lrow = lane >> 4, lcol = lane & 15;
  facc acc[4][4] = {};

  // stage K-tile t into buffer buf: 8 chunks x 64 slots x 16B per matrix.
  // LDS dst is wave-uniform base (+ lane*16 by HW); global src per-lane.
  auto stage = [&](int t, int buf){
    const int k0 = t * 32;
#pragma unroll
    for (int i = 0; i < 2; ++i){
      const int chunk = wave*2 + i;            // 0..7
      const int slot  = chunk*64 + lane;       // 0..511
      const int row   = slot >> 2, col8 = (slot & 3) * 8;
      const ushort* ga = A  + (size_t)(m0 + row) * K + k0 + col8;
      const ushort* gb = Bt + (size_t)(n0 + row) * K + k0 + col8;
      __builtin_amdgcn_global_load_lds((const AS1 void*)ga,
          (AS3 void*)(&As[buf][chunk*512]), 16, 0, 0);
      __builtin_amdgcn_global_load_lds((const AS1 void*)gb,
          (AS3 void*)(&Bs[buf][chunk*512]), 16, 0, 0);
    }
  };

  stage(0, 0);
  __syncthreads();
  const int nT = K >> 5;
  for (int t = 0; t < nT; ++t){
    const int buf = t & 1;
    if (t + 1 < nT) stage(t + 1, buf ^ 1);   // prefetch next tile (other buffer)
    bfrag af[4], bf[4];
#pragma unroll
    for (int mi = 0; mi < 4; ++mi)
      af[mi] = *(const bfrag*)(&As[buf][(wm*64 + mi*16 + lcol)*32 + lrow*8]);
#pragma unroll
    for (int ni = 0; ni < 4; ++ni)
      bf[ni] = *(const bfrag*)(&Bs[buf][(wn*64 + ni*16 + lcol)*32 + lrow*8]);
#pragma unroll
    for (int mi = 0; mi < 4; ++mi)
#pragma unroll
      for (int ni = 0; ni < 4; ++ni)
        acc[mi][ni] = __builtin_amdgcn_mfma_f32_16x16x32_bf16(af[mi], bf[ni], acc[mi][ni], 0, 0, 0);
    __syncthreads();                         // drains prefetch loads + LDS reads
  }
#pragma unroll
  for (int mi = 0; mi < 4; ++mi){
#pragma unroll
    for (int ni = 0; ni < 4; ++ni){
      const int col = n0 + wn*64 + ni*16 + lcol;
      const float bsv = HAS_BIAS ? bias[col] : 0.f;
#pragma unroll
      for (int r = 0; r < 4; ++r){
        const size_t row = (size_t)m0 + wm*64 + mi*16 + lrow*4 + r;
        const float v = acc[mi][ni][r] + bsv;
        if (OUT_BF16) ((ushort*)Cout)[row * N + col] = f2bf(v);
        else          ((float*) Cout)[row * N + col] = v;
      }
    }
  }
}

// ---- in-place RoPE on q (cols 0..2047) and k (cols 2048..2303) of qkv ----
__global__ void k_rope(ushort* __restrict__ qkv, const float* __restrict__ cosb,
                       const float* __restrict__ sinb){
  const int s = blockIdx.x, b = blockIdx.y;
  ushort* rp = qkv + ((size_t)(b*Ssz + s)) * NQKV;
  const float* cb = cosb + s*64;
  const float* sb = sinb + s*64;
  for (int i = threadIdx.x; i < 18*64; i += 256){  // 16 q-heads + 2 kv-heads
    const int hh = i >> 6, d = i & 63;
    ushort* p = rp + hh*128 + d;
    const float x1 = bf2f(p[0]), x2 = bf2f(p[64]);
    const float c = cb[d], sn = sb[d];
    p[0]  = f2bf(x1*c  - x2*sn);
    p[64] = f2bf(x1*sn + x2*c);
  }
}

// ---- V relayout: qkv cols [2304,2560) (b,s,kv,d) -> vt (b,kv,d,s) ----
__global__ void k_vt(const ushort* __restrict__ qkv, ushort* __restrict__ vt){
  __shared__ ushort t[64][65];
  const int s0 = blockIdx.x * 64, d0 = blockIdx.y * 64;
  const int bkv = blockIdx.z, b = bkv >> 1, kv = bkv & 1;
  for (int i = threadIdx.x; i < 4096; i += 256){
    const int sl = i >> 6, dl = i & 63;
    t[sl][dl] = qkv[(size_t)(b*Ssz + s0 + sl)*NQKV + 2304 + kv*128 + d0 + dl];
  }
  __syncthreads();
  for (int i = threadIdx.x; i < 4096; i += 256){
    const int dl = i >> 6, sl = i & 63;
    vt[((size_t)(bkv*128 + d0 + dl))*Ssz + s0 + sl] = t[sl][dl];
  }
}

// ---- causal GQA flash attention, 8-wave blocks, SWAPPED QK^T softmax ----
// NEW (round 8): complementary pairing across blockIdx.z. Co-resident blocks
// (idx c, c+256) differ only in b; mapping p = b ? 15-x : x makes their loop
// lengths (32-x) + (17+x) = 49 = constant -> every CU finishes together.
// (Placement heuristic only; correctness independent of wg->CU assignment.)
__global__ __launch_bounds__(512, 4) void k_attn(const ushort* __restrict__ qkv,
                                                 const ushort* __restrict__ vt,
                                                 ushort* __restrict__ out){
  __shared__ __attribute__((aligned(16))) char klds2[2*16384];  // K dbuf, 64 rows x 256B, swizzled
  __shared__ __attribute__((aligned(16))) char vlds[128*144];   // V^T 128 x (64 bf16 + 16B pad)
  __shared__ __attribute__((aligned(16))) char plds[8*2304];    // per-wave P 16 x (64 bf16 + pad)
  const int bx = blockIdx.x, h = blockIdx.y, b = blockIdx.z;
  const int p = b ? (15 - bx) : bx;               // complementary pair swizzle
  const int qtA = p, qtB = 31 - p;                // qtB >= 16 > qtA <= 15 always
  const int kvh = h >> 3;                         // rep = NH/NKV = 8
  const int tid = threadIdx.x, wave = tid >> 6, lane = tid & 63;
  const int grp = wave >> 2, w4 = wave & 3;       // grp 0 -> tile B, grp 1 -> tile A
  const int qx = grp ? qtA : qtB;
  const int lrow = lane >> 4, lcol = lane & 15;

  bfrag qf[4];
  {
    const ushort* qp = qkv + ((size_t)b*Ssz + qx*64 + w4*16 + lcol)*NQKV + h*HDd + lrow*8;
#pragma unroll
    for (int kk = 0; kk < 4; ++kk) qf[kk] = *(const bfrag*)(qp + kk*32);
  }
  facc acc[8] = {};
  float m = -1e30f, l = 0.f;               // per-lane softmax state for q = lcol (log2 domain)

  const ushort* kb = qkv + (size_t)b*Ssz*NQKV + Hsz + kvh*HDd;
  const ushort* vb = vt + ((size_t)(b*NKVh + kvh))*HDd*Ssz;
  char* pw = plds + wave*2304;
  const int qloc = w4*16 + lcol;           // this lane's q row within the 64-row q-tile

  auto issueK = [&](int t, char* dst){
    const ushort* kt = kb + (size_t)t*64*NQKV;
#pragma unroll
    for (int i = 0; i < 2; ++i){
      const int row = i*32 + wave*4 + (lane >> 4);
      const int cb  = (lane & 15) * 16;
      const char* g = (const char*)(kt + (size_t)row*NQKV) + (cb ^ ((row & 7) << 4));
      __builtin_amdgcn_global_load_lds((const AS1 void*)g,
          (AS3 void*)(dst + i*8192 + wave*1024), 16, 0, 0);
    }
  };

  int4 vreg[2];                          // V staging registers (T14 split)
  auto loadV = [&](int t){
#pragma unroll
    for (int i = 0; i < 2; ++i){
      const int c = i*512 + tid;
      vreg[i] = *(const int4*)((const char*)(vb + (size_t)(c>>3)*Ssz + t*64) + (c&7)*16);
    }
  };
  auto writeV = [&](){
#pragma unroll
    for (int i = 0; i < 2; ++i){
      const int c = i*512 + tid;
      *(int4*)(vlds + (c>>3)*144 + (c&7)*16) = vreg[i];
    }
  };

  auto step = [&](int t, const char* kcur){
    facc sc[4] = {};
#pragma unroll
    for (int kk = 0; kk < 4; ++kk){        // S^T = K·Q^T: 16 MFMA, swizzled K reads
#pragma unroll
      for (int nt = 0; nt < 4; ++nt){
        const bfrag kf = *(const bfrag*)(kcur + (nt*16 + lcol)*256 +
                                         ((kk*64 + lrow*16) ^ ((lcol & 7) << 4)));
        sc[nt] = __builtin_amdgcn_mfma_f32_16x16x32_bf16(kf, qf[kk], sc[nt], 0, 0, 0);
      }
    }
    const bool diag = (t == qx);
    float e[4][4];
    float tm = -1e30f;
#pragma unroll
    for (int nt = 0; nt < 4; ++nt){
#pragma unroll
      for (int r = 0; r < 4; ++r){
        float sv = sc[nt][r] * 0.12752585778442352f;   // log2(e)/sqrt(128)
        if (diag && (nt*16 + lrow*4 + r) > qloc) sv = -1e30f;
        e[nt][r] = sv;
        tm = fmaxf(tm, sv);
      }
    }
    tm = fmaxf(tm, __shfl_xor(tm, 16));    // reduce over the 4 k-groups
    tm = fmaxf(tm, __shfl_xor(tm, 32));
    float mn = m, corr = 1.f;
    if (!__all(tm <= m + 11.5f)){          // defer-max: skip rescale when bounded
      mn = fmaxf(m, tm);
      corr = exp2f(m - mn);
#pragma unroll
      for (int r = 0; r < 4; ++r){
        const float ct = __shfl(corr, lrow*4 + r);
#pragma unroll
        for (int dt = 0; dt < 8; ++dt) acc[dt][r] *= ct;
      }
      m = mn;
    }
    float rs = 0.f;
#pragma unroll
    for (int nt = 0; nt < 4; ++nt)
#pragma unroll
      for (int r = 0; r < 4; ++r){
        const float ev = exp2f(e[nt][r] - mn);
        e[nt][r] = ev; rs += ev;
      }
    rs += __shfl_xor(rs, 16);
    rs += __shfl_xor(rs, 32);
    l = l*corr + rs;
#pragma unroll
    for (int nt = 0; nt < 4; ++nt){        // P[q][k] -> LDS: 4 x ds_write_b64
      ushort4 w;
      w.x = f2bf(e[nt][0]); w.y = f2bf(e[nt][1]);
      w.z = f2bf(e[nt][2]); w.w = f2bf(e[nt][3]);
      *(ushort4*)(pw + lcol*144 + nt*32 + lrow*8) = w;
    }
    asm volatile("s_waitcnt lgkmcnt(0)" ::: "memory");
#pragma unroll
    for (int kk2 = 0; kk2 < 2; ++kk2){     // PV: 16 MFMA
      const bfrag pa = *(const bfrag*)(pw + lcol*144 + kk2*64 + lrow*16);
#pragma unroll
      for (int dt = 0; dt < 8; ++dt){
        const bfrag vf = *(const bfrag*)(vlds + (dt*16 + lcol)*144 + kk2*64 + lrow*16);
        acc[dt] = __builtin_amdgcn_mfma_f32_16x16x32_bf16(pa, vf, acc[dt], 0, 0, 0);
      }
    }
  };

  // prologue: tile 0
  issueK(0, klds2);
  loadV(0);
  writeV();
  __syncthreads();                         // drains K DMA (vmcnt) + V writes (lgkm)

  int cur = 0;
  for (int t = 0; t <= qtB; ++t){
    const bool more = (t < qtB);
    if (more){
      issueK(t + 1, klds2 + (cur ^ 1)*16384);  // DMA next K tile into other buffer
      loadV(t + 1);                            // V loads in flight under compute
    }
    if (t <= qx) step(t, klds2 + cur*16384);
    __syncthreads();                       // all reads done; K DMA + V loads drained
    if (more) writeV();
    __syncthreads();                       // vlds(t+1) visible to all waves
    cur ^= 1;
  }

  float lt[4];
#pragma unroll
  for (int r = 0; r < 4; ++r) lt[r] = __shfl(l, lrow*4 + r);
#pragma unroll
  for (int r = 0; r < 4; ++r){
    const float inv = 1.f / lt[r];
    ushort* op = out + ((size_t)b*Ssz + qx*64 + w4*16 + lrow*4 + r)*Hsz + h*HDd;
#pragma unroll
    for (int dt = 0; dt < 8; ++dt)
      op[dt*16 + lcol] = f2bf(acc[dt][r] * inv);
  }
}

extern "C" void kernel_launch(void* const* d_in, const int* in_sizes, int n_in,
                              void* d_out, int out_size, void* d_ws, size_t ws_size,
                              hipStream_t stream){
  (void)in_sizes; (void)n_in; (void)out_size;
  const float* hs  = (const float*)d_in[0];
  // d_in[1] = attention_mask: exactly causal 0/-1e9, applied analytically in k_attn
  const int*   pos = (const int*)  d_in[2];
  const float* Wq  = (const float*)d_in[3];
  const float* bq  = (const float*)d_in[4];
  const float* Wk  = (const float*)d_in[5];
  const float* bk  = (const float*)d_in[6];
  const float* Wv  = (const float*)d_in[7];
  const float* bv  = (const float*)d_in[8];
  const float* Wo  = (const float*)d_in[9];

  if (ws_size < 59779072) return;  // need ~57 MB scratch

  char* ws = (char*)d_ws;
  ushort* Xbf   = (ushort*)(ws + 0);          // 16,777,216 B; reused as attn output
  ushort* WqkvT = (ushort*)(ws + 16777216);   // 10,485,760 B (2560 x 2048 bf16)
  ushort* WoT   = (ushort*)(ws + 27262976);   //  8,388,608 B
  float*  bqkv  = (float*) (ws + 35651584);   //     10,240 B
  float*  cosb  = (float*) (ws + 35661824);   //    524,288 B
  float*  sinb  = (float*) (ws + 36186112);   //    524,288 B
  ushort* qkv   = (ushort*)(ws + 36710400);   // 20,971,520 B (4096 x 2560 bf16)
  ushort* vt    = (ushort*)(ws + 57681920);   //  2,097,152 B
  ushort* attn  = Xbf;

  k_convert  <<<8192, 256, 0, stream>>>(hs, Xbf);
  k_transpose<<<dim3(64,64), dim3(32,8), 0, stream>>>(Wq, WqkvT, 2048, 0);
  k_transpose<<<dim3(64, 8), dim3(32,8), 0, stream>>>(Wk, WqkvT, 256, 2048);
  k_transpose<<<dim3(64, 8), dim3(32,8), 0, stream>>>(Wv, WqkvT, 256, 2304);
  k_transpose<<<dim3(64,64), dim3(32,8), 0, stream>>>(Wo, WoT, 2048, 0);
  k_bias     <<<10, 256, 0, stream>>>(bq, bk, bv, bqkv);
  k_ropetab  <<<2048, 64, 0, stream>>>(pos, cosb, sinb);
  k_gemm<true,  true ><<<dim3(32,20), 256, 0, stream>>>(Xbf, WqkvT, bqkv, qkv, 2560, 2048);
  k_rope     <<<dim3(2048,2), 256, 0, stream>>>(qkv, cosb, sinb);
  k_vt       <<<dim3(32,2,4), 256, 0, stream>>>(qkv, vt);
  k_attn     <<<dim3(16,16,2), 512, 0, stream>>>(qkv, vt, attn);
  k_gemm<false, false><<<dim3(32,16), 256, 0, stream>>>(attn, WoT, nullptr, d_out, 2048, 2048);
}